// Round 1
// baseline (1332.581 us; speedup 1.0000x reference)
//
#include <hip/hip_runtime.h>

#define N_NODES 20000
#define N_EDGES 320000
#define HD 256
#define NLAYERS 7
#define NGRAPH 512
#define NOUT 128

// ---------------- CSR build ----------------
__global__ __launch_bounds__(256) void hist_kernel(const int* __restrict__ dst, int* __restrict__ hist) {
    int e = blockIdx.x * 256 + threadIdx.x;
    if (e < N_EDGES) atomicAdd(&hist[dst[e]], 1);
}

__global__ __launch_bounds__(1024) void scan_kernel(const int* __restrict__ hist,
                                                    int* __restrict__ row_ptr,
                                                    int* __restrict__ cursor) {
    __shared__ int sums[1024];
    int t = threadIdx.x;
    const int CH = 20;  // 1024*20 = 20480 >= 20000
    int base = t * CH;
    int local[20];
    int s = 0;
#pragma unroll
    for (int i = 0; i < CH; i++) {
        int v = (base + i < N_NODES) ? hist[base + i] : 0;
        local[i] = s;
        s += v;
    }
    sums[t] = s;
    __syncthreads();
    for (int off = 1; off < 1024; off <<= 1) {
        int v = (t >= off) ? sums[t - off] : 0;
        __syncthreads();
        sums[t] += v;
        __syncthreads();
    }
    int offset = (t == 0) ? 0 : sums[t - 1];
#pragma unroll
    for (int i = 0; i < CH; i++) {
        int idx = base + i;
        if (idx < N_NODES) {
            int v = offset + local[i];
            row_ptr[idx] = v;
            cursor[idx] = v;
        }
    }
    if (t == 1023) row_ptr[N_NODES] = sums[1023];
}

__global__ __launch_bounds__(256) void scatter_kernel(const int* __restrict__ dst,
                                                      const int* __restrict__ src,
                                                      const int* __restrict__ ef,
                                                      int* __restrict__ cursor,
                                                      int* __restrict__ src_sorted,
                                                      int* __restrict__ combo_sorted) {
    int e = blockIdx.x * 256 + threadIdx.x;
    if (e < N_EDGES) {
        int d = dst[e];
        int p = atomicAdd(&cursor[d], 1);
        src_sorted[p] = src[e];
        combo_sorted[p] = ef[e * 3] * 25 + ef[e * 3 + 1] * 5 + ef[e * 3 + 2];
    }
}

// ---------------- bond-embedding combo tables: [L][125][H] ----------------
__global__ __launch_bounds__(256) void hetab_kernel(const float* __restrict__ bond,
                                                    float* __restrict__ he) {
    int idx = blockIdx.x * 256 + threadIdx.x;
    if (idx >= NLAYERS * 125 * HD) return;
    int h = idx & (HD - 1);
    int rem = idx >> 8;          // l*125 + c
    int l = rem / 125;
    int c = rem - l * 125;
    int f0 = c / 25, f1 = (c / 5) % 5, f2 = c % 5;
    const float* b = bond + (size_t)l * 3 * 8 * HD;
    he[idx] = b[(0 * 8 + f0) * HD + h] + b[(1 * 8 + f1) * HD + h] + b[(2 * 8 + f2) * HD + h];
}

// ---------------- atom encoder + layer-0 BN stats ----------------
__global__ __launch_bounds__(256) void atom_kernel(const int* __restrict__ nf,
                                                   const float* __restrict__ emb,
                                                   float* __restrict__ hv,
                                                   float* __restrict__ stats0) {
    int c = threadIdx.x;
    int n0 = blockIdx.x * 32;
    float s1 = 0.f, s2 = 0.f;
    for (int i = 0; i < 32; i++) {
        int n = n0 + i;
        const int* f = nf + n * 9;
        float v = 0.f;
#pragma unroll
        for (int j = 0; j < 9; j++) v += emb[(j * 128 + f[j]) * HD + c];
        hv[(size_t)n * HD + c] = v;
        s1 += v;
        s2 += v * v;
    }
    atomicAdd(&stats0[c], s1);
    atomicAdd(&stats0[HD + c], s2);
}

// ---------------- per-layer edge pass: BN inline + online edge-softmax + x = h1 + agg ----
__global__ __launch_bounds__(256) void edge_kernel(const float* __restrict__ hv,
                                                   float* __restrict__ x,
                                                   const int* __restrict__ row_ptr,
                                                   const int* __restrict__ src_sorted,
                                                   const int* __restrict__ combo_sorted,
                                                   const float* __restrict__ hetab,
                                                   const float* __restrict__ stats,
                                                   const float* __restrict__ gamma,
                                                   const float* __restrict__ beta) {
    int n = blockIdx.x;
    int c = threadIdx.x;
    float mu = stats[c] * (1.0f / N_NODES);
    float var = stats[HD + c] * (1.0f / N_NODES) - mu * mu;
    float rs = rsqrtf(fmaxf(var, 0.0f) + 1e-5f);
    float a = gamma[c] * rs;
    float b = beta[c] - mu * a;

    int e0 = row_ptr[n], e1 = row_ptr[n + 1];
    float M = -1e30f, S = 0.f, T = 0.f;
    for (int e = e0; e < e1; e++) {
        int s = src_sorted[e];
        int cb = combo_sorted[e];
        float h1s = fmaxf(fmaf(hv[(size_t)s * HD + c], a, b), 0.f);
        float m = fmaxf(h1s + hetab[cb * HD + c], 0.f) + 1e-7f;
        float nM = fmaxf(M, m);
        float sc = __expf(M - nM);
        float ee = __expf(m - nM);
        S = S * sc + ee;
        T = T * sc + m * ee;
        M = nM;
    }
    float agg = (S > 0.f) ? (T / S) : 0.f;
    float own = fmaxf(fmaf(hv[(size_t)n * HD + c], a, b), 0.f);
    x[(size_t)n * HD + c] = own + agg;
}

// ---------------- MLP + residual + next-layer BN stats ----------------
__global__ __launch_bounds__(256) void mlp_kernel(const float* __restrict__ x,
                                                  float* __restrict__ hv,
                                                  const float* __restrict__ W,
                                                  const float* __restrict__ bias,
                                                  float* __restrict__ stats_next,
                                                  int accum_stats) {
    __shared__ float xs[32][HD];  // 32 KB
    int c = threadIdx.x;
    int row0 = blockIdx.x * 32;
    for (int i = 0; i < 32; i++) xs[i][c] = x[(size_t)(row0 + i) * HD + c];
    __syncthreads();

    float acc[32];
#pragma unroll
    for (int r = 0; r < 32; r++) acc[r] = 0.f;

    for (int k4 = 0; k4 < HD / 4; k4++) {
        float w0 = W[(k4 * 4 + 0) * HD + c];
        float w1 = W[(k4 * 4 + 1) * HD + c];
        float w2 = W[(k4 * 4 + 2) * HD + c];
        float w3 = W[(k4 * 4 + 3) * HD + c];
#pragma unroll
        for (int r = 0; r < 32; r++) {
            const float4 xv = *reinterpret_cast<const float4*>(&xs[r][k4 * 4]);
            acc[r] = fmaf(xv.x, w0, fmaf(xv.y, w1, fmaf(xv.z, w2, fmaf(xv.w, w3, acc[r]))));
        }
    }

    float bi = bias[c];
    float s1 = 0.f, s2 = 0.f;
    for (int r = 0; r < 32; r++) {
        size_t idx = (size_t)(row0 + r) * HD + c;
        float nv = acc[r] + bi + hv[idx];
        hv[idx] = nv;
        s1 += nv;
        s2 += nv * nv;
    }
    if (accum_stats) {
        atomicAdd(&stats_next[c], s1);
        atomicAdd(&stats_next[HD + c], s2);
    }
}

// ---------------- graph mean-pool (run-length compressed atomics) ----------------
__global__ __launch_bounds__(256) void pool_kernel(const float* __restrict__ hv,
                                                   const int* __restrict__ gid,
                                                   float* __restrict__ hg,
                                                   float* __restrict__ cnt) {
    int c = threadIdx.x;
    int n0 = blockIdx.x * 32;
    int curg = gid[n0];
    float s = 0.f;
    int runlen = 0;
    for (int i = 0; i < 32; i++) {
        int n = n0 + i;
        int g = gid[n];
        if (g != curg) {
            atomicAdd(&hg[curg * HD + c], s);
            if (c == 0) atomicAdd(&cnt[curg], (float)runlen);
            curg = g;
            s = 0.f;
            runlen = 0;
        }
        s += hv[(size_t)n * HD + c];
        runlen++;
    }
    atomicAdd(&hg[curg * HD + c], s);
    if (c == 0) atomicAdd(&cnt[curg], (float)runlen);
}

// ---------------- final projection ----------------
__global__ __launch_bounds__(128) void out_kernel(const float* __restrict__ hg,
                                                  const float* __restrict__ cnt,
                                                  const float* __restrict__ wout,
                                                  const float* __restrict__ bout,
                                                  float* __restrict__ out) {
    __shared__ float hr[HD];
    int g = blockIdx.x, o = threadIdx.x;
    float inv = 1.0f / fmaxf(cnt[g], 1.0f);
    hr[o] = hg[g * HD + o] * inv;
    hr[o + 128] = hg[g * HD + o + 128] * inv;
    __syncthreads();
    float acc = bout[o];
#pragma unroll 4
    for (int k = 0; k < HD; k++) acc = fmaf(hr[k], wout[k * NOUT + o], acc);
    out[g * NOUT + o] = acc;
}

extern "C" void kernel_launch(void* const* d_in, const int* in_sizes, int n_in,
                              void* d_out, int out_size, void* d_ws, size_t ws_size,
                              hipStream_t stream) {
    const int* node_feats = (const int*)d_in[0];
    const int* edge_feats = (const int*)d_in[1];
    const int* src = (const int*)d_in[2];
    const int* dst = (const int*)d_in[3];
    const int* gid = (const int*)d_in[4];
    const float* atom_emb = (const float*)d_in[5];
    const float* bond_emb = (const float*)d_in[6];
    const float* gamma = (const float*)d_in[7];
    const float* beta = (const float*)d_in[8];
    const float* mlp_w = (const float*)d_in[9];
    const float* mlp_b = (const float*)d_in[10];
    const float* w_out = (const float*)d_in[11];
    const float* b_out = (const float*)d_in[12];
    float* out = (float*)d_out;

    float* ws = (float*)d_ws;
    float* hv = ws;
    float* x = hv + (size_t)N_NODES * HD;
    float* hetabs = x + (size_t)N_NODES * HD;
    int* row_ptr = (int*)(hetabs + NLAYERS * 125 * HD);
    int* cursor = row_ptr + (N_NODES + 1);
    int* src_sorted = cursor + N_NODES;
    int* combo_sorted = src_sorted + N_EDGES;
    int* hist = combo_sorted + N_EDGES;
    float* stats = (float*)(hist + N_NODES);        // [NLAYERS][2][HD]
    float* hg = stats + NLAYERS * 2 * HD;           // [NGRAPH][HD]
    float* cnt = hg + NGRAPH * HD;                  // [NGRAPH]

    size_t zero_bytes = (size_t)(N_NODES + NLAYERS * 2 * HD + NGRAPH * HD + NGRAPH) * 4;
    hipMemsetAsync(hist, 0, zero_bytes, stream);

    hist_kernel<<<(N_EDGES + 255) / 256, 256, 0, stream>>>(dst, hist);
    scan_kernel<<<1, 1024, 0, stream>>>(hist, row_ptr, cursor);
    scatter_kernel<<<(N_EDGES + 255) / 256, 256, 0, stream>>>(dst, src, edge_feats, cursor,
                                                              src_sorted, combo_sorted);
    hetab_kernel<<<(NLAYERS * 125 * HD + 255) / 256, 256, 0, stream>>>(bond_emb, hetabs);
    atom_kernel<<<N_NODES / 32, 256, 0, stream>>>(node_feats, atom_emb, hv, stats);

    for (int l = 0; l < NLAYERS; l++) {
        edge_kernel<<<N_NODES, 256, 0, stream>>>(hv, x, row_ptr, src_sorted, combo_sorted,
                                                 hetabs + l * 125 * HD, stats + l * 2 * HD,
                                                 gamma + l * HD, beta + l * HD);
        mlp_kernel<<<N_NODES / 32, 256, 0, stream>>>(x, hv, mlp_w + (size_t)l * HD * HD,
                                                     mlp_b + l * HD, stats + (l + 1) * 2 * HD,
                                                     (l < NLAYERS - 1) ? 1 : 0);
    }

    pool_kernel<<<N_NODES / 32, 256, 0, stream>>>(hv, gid, hg, cnt);
    out_kernel<<<NGRAPH, 128, 0, stream>>>(hg, cnt, w_out, b_out, out);
}

// Round 3
// 1019.141 us; speedup vs baseline: 1.3076x; 1.3076x over previous
//
#include <hip/hip_runtime.h>

#define N_NODES 20000
#define N_EDGES 320000
#define HD 256
#define NLAYERS 7
#define NGRAPH 512
#define NOUT 128

typedef __attribute__((ext_vector_type(8))) short bf16x8;
typedef __attribute__((ext_vector_type(4))) int i32x4;
typedef __attribute__((ext_vector_type(4))) float f32x4;

__device__ __forceinline__ ushort f2bf(float f) {
    union { float f; unsigned u; } v;
    v.f = f;
    unsigned r = (v.u + 0x7FFFu + ((v.u >> 16) & 1u)) >> 16;
    return (ushort)r;
}

// ---------------- CSR build ----------------
__global__ __launch_bounds__(256) void hist_kernel(const int* __restrict__ dst, int* __restrict__ hist) {
    int e = blockIdx.x * 256 + threadIdx.x;
    if (e < N_EDGES) atomicAdd(&hist[dst[e]], 1);
}

__global__ __launch_bounds__(1024) void scan_kernel(const int* __restrict__ hist,
                                                    int* __restrict__ row_ptr,
                                                    int* __restrict__ cursor) {
    __shared__ int sums[1024];
    int t = threadIdx.x;
    const int CH = 20;
    int base = t * CH;
    int local[20];
    int s = 0;
#pragma unroll
    for (int i = 0; i < CH; i++) {
        int v = (base + i < N_NODES) ? hist[base + i] : 0;
        local[i] = s;
        s += v;
    }
    sums[t] = s;
    __syncthreads();
    for (int off = 1; off < 1024; off <<= 1) {
        int v = (t >= off) ? sums[t - off] : 0;
        __syncthreads();
        sums[t] += v;
        __syncthreads();
    }
    int offset = (t == 0) ? 0 : sums[t - 1];
#pragma unroll
    for (int i = 0; i < CH; i++) {
        int idx = base + i;
        if (idx < N_NODES) {
            int v = offset + local[i];
            row_ptr[idx] = v;
            cursor[idx] = v;
        }
    }
    if (t == 1023) row_ptr[N_NODES] = sums[1023];
}

__global__ __launch_bounds__(256) void scatter_kernel(const int* __restrict__ dst,
                                                      const int* __restrict__ src,
                                                      const int* __restrict__ ef,
                                                      int* __restrict__ cursor,
                                                      int* __restrict__ src_sorted,
                                                      int* __restrict__ combo_sorted) {
    int e = blockIdx.x * 256 + threadIdx.x;
    if (e < N_EDGES) {
        int d = dst[e];
        int p = atomicAdd(&cursor[d], 1);
        src_sorted[p] = src[e];
        combo_sorted[p] = ef[e * 3] * 25 + ef[e * 3 + 1] * 5 + ef[e * 3 + 2];
    }
}

// ---------------- bond-embedding combo tables: [L][125][H] ----------------
__global__ __launch_bounds__(256) void hetab_kernel(const float* __restrict__ bond,
                                                    float* __restrict__ he) {
    int idx = blockIdx.x * 256 + threadIdx.x;
    if (idx >= NLAYERS * 125 * HD) return;
    int h = idx & (HD - 1);
    int rem = idx >> 8;
    int l = rem / 125;
    int c = rem - l * 125;
    int f0 = c / 25, f1 = (c / 5) % 5, f2 = c % 5;
    const float* b = bond + (size_t)l * 3 * 8 * HD;
    he[idx] = b[(0 * 8 + f0) * HD + h] + b[(1 * 8 + f1) * HD + h] + b[(2 * 8 + f2) * HD + h];
}

// ---------------- W -> Wt bf16 transpose: Wt[l][n][k] ----------------
__global__ __launch_bounds__(256) void wt_kernel(const float* __restrict__ W,
                                                 ushort* __restrict__ Wt) {
    int b = blockIdx.x;
    int l = b >> 8;
    int n = b & 255;
    int k = threadIdx.x;
    float v = W[((size_t)l * HD + k) * HD + n];
    Wt[((size_t)l * HD + n) * HD + k] = f2bf(v);
}

// ---------------- atom encoder + layer-0 BN stats ----------------
__global__ __launch_bounds__(256) void atom_kernel(const int* __restrict__ nf,
                                                   const float* __restrict__ emb,
                                                   float* __restrict__ hv,
                                                   float* __restrict__ stats0) {
    int c = threadIdx.x;
    int n0 = blockIdx.x * 32;
    float s1 = 0.f, s2 = 0.f;
    for (int i = 0; i < 32; i++) {
        int n = n0 + i;
        const int* f = nf + n * 9;
        float v = 0.f;
#pragma unroll
        for (int j = 0; j < 9; j++) v += emb[(j * 128 + f[j]) * HD + c];
        hv[(size_t)n * HD + c] = v;
        s1 += v;
        s2 += v * v;
    }
    atomicAdd(&stats0[c], s1);
    atomicAdd(&stats0[HD + c], s2);
}

// ---------------- per-layer edge pass (unchanged) ----------------
__global__ __launch_bounds__(256) void edge_kernel(const float* __restrict__ hv,
                                                   float* __restrict__ x,
                                                   const int* __restrict__ row_ptr,
                                                   const int* __restrict__ src_sorted,
                                                   const int* __restrict__ combo_sorted,
                                                   const float* __restrict__ hetab,
                                                   const float* __restrict__ stats,
                                                   const float* __restrict__ gamma,
                                                   const float* __restrict__ beta) {
    int n = blockIdx.x;
    int c = threadIdx.x;
    float mu = stats[c] * (1.0f / N_NODES);
    float var = stats[HD + c] * (1.0f / N_NODES) - mu * mu;
    float rs = rsqrtf(fmaxf(var, 0.0f) + 1e-5f);
    float a = gamma[c] * rs;
    float b = beta[c] - mu * a;

    int e0 = row_ptr[n], e1 = row_ptr[n + 1];
    float M = -1e30f, S = 0.f, T = 0.f;
    for (int e = e0; e < e1; e++) {
        int s = src_sorted[e];
        int cb = combo_sorted[e];
        float h1s = fmaxf(fmaf(hv[(size_t)s * HD + c], a, b), 0.f);
        float m = fmaxf(h1s + hetab[cb * HD + c], 0.f) + 1e-7f;
        float nM = fmaxf(M, m);
        float sc = __expf(M - nM);
        float ee = __expf(m - nM);
        S = S * sc + ee;
        T = T * sc + m * ee;
        M = nM;
    }
    float agg = (S > 0.f) ? (T / S) : 0.f;
    float own = fmaxf(fmaf(hv[(size_t)n * HD + c], a, b), 0.f);
    x[(size_t)n * HD + c] = own + agg;
}

// ---------------- MFMA MLP: hv += x @ W + b, fused BN stats ----------------
__global__ __launch_bounds__(256) void mlp_mfma_kernel(const float* __restrict__ x,
                                                       float* __restrict__ hv,
                                                       const ushort* __restrict__ Wt,
                                                       const float* __restrict__ bias,
                                                       float* __restrict__ stats_next,
                                                       int accum_stats) {
    // 32 rows x 256 cols per block; 4 waves, wave w owns cols [64w, 64w+64)
    __shared__ __attribute__((aligned(16))) ushort xs[32 * 256];  // bf16, XOR-swizzled 16B units

    int t = threadIdx.x;
    int row0 = blockIdx.x * 32;
    const float* xbase = x + (size_t)row0 * HD;

    // stage x -> bf16 LDS.  unit = 8 bf16 = 16B; swizzle unit ^= (row&7)
#pragma unroll
    for (int i = 0; i < 4; i++) {
        int flat = i * 2048 + t * 8;
        float4 f0 = *reinterpret_cast<const float4*>(xbase + flat);
        float4 f1 = *reinterpret_cast<const float4*>(xbase + flat + 4);
        i32x4 iv;
        iv.x = (int)f2bf(f0.x) | ((int)f2bf(f0.y) << 16);
        iv.y = (int)f2bf(f0.z) | ((int)f2bf(f0.w) << 16);
        iv.z = (int)f2bf(f1.x) | ((int)f2bf(f1.y) << 16);
        iv.w = (int)f2bf(f1.z) | ((int)f2bf(f1.w) << 16);
        int row = flat >> 8;
        int k8 = (flat >> 3) & 31;
        int sw = k8 ^ (row & 7);
        *reinterpret_cast<i32x4*>(&xs[row * 256 + sw * 8]) = iv;
    }
    __syncthreads();

    int l = t & 63;
    int w = t >> 6;
    int kg = l >> 4;         // k-group 0..3
    int lr = l & 15;         // row (A) / col (B/D) within tile

    f32x4 acc[2][4];
#pragma unroll
    for (int m = 0; m < 2; m++)
#pragma unroll
        for (int n = 0; n < 4; n++) acc[m][n] = (f32x4){0.f, 0.f, 0.f, 0.f};

    const ushort* wcol = Wt + (size_t)(w * 64 + lr) * HD;

#pragma unroll
    for (int ks = 0; ks < 8; ks++) {
        int unit = ks * 4 + kg;
        int rA0 = lr, rA1 = 16 + lr;
        bf16x8 a0 = *reinterpret_cast<const bf16x8*>(&xs[rA0 * 256 + (unit ^ (rA0 & 7)) * 8]);
        bf16x8 a1 = *reinterpret_cast<const bf16x8*>(&xs[rA1 * 256 + (unit ^ (rA1 & 7)) * 8]);
        int kk = ks * 32 + kg * 8;
        bf16x8 b0 = *reinterpret_cast<const bf16x8*>(wcol + kk);
        bf16x8 b1 = *reinterpret_cast<const bf16x8*>(wcol + 16 * HD + kk);
        bf16x8 b2 = *reinterpret_cast<const bf16x8*>(wcol + 32 * HD + kk);
        bf16x8 b3 = *reinterpret_cast<const bf16x8*>(wcol + 48 * HD + kk);
        acc[0][0] = __builtin_amdgcn_mfma_f32_16x16x32_bf16(a0, b0, acc[0][0], 0, 0, 0);
        acc[0][1] = __builtin_amdgcn_mfma_f32_16x16x32_bf16(a0, b1, acc[0][1], 0, 0, 0);
        acc[0][2] = __builtin_amdgcn_mfma_f32_16x16x32_bf16(a0, b2, acc[0][2], 0, 0, 0);
        acc[0][3] = __builtin_amdgcn_mfma_f32_16x16x32_bf16(a0, b3, acc[0][3], 0, 0, 0);
        acc[1][0] = __builtin_amdgcn_mfma_f32_16x16x32_bf16(a1, b0, acc[1][0], 0, 0, 0);
        acc[1][1] = __builtin_amdgcn_mfma_f32_16x16x32_bf16(a1, b1, acc[1][1], 0, 0, 0);
        acc[1][2] = __builtin_amdgcn_mfma_f32_16x16x32_bf16(a1, b2, acc[1][2], 0, 0, 0);
        acc[1][3] = __builtin_amdgcn_mfma_f32_16x16x32_bf16(a1, b3, acc[1][3], 0, 0, 0);
    }

    // epilogue: bias + residual + BN stats.  D layout: col=lr, row=kg*4+reg
    float bcol[4], s1[4], s2[4];
#pragma unroll
    for (int nt = 0; nt < 4; nt++) {
        bcol[nt] = bias[w * 64 + nt * 16 + lr];
        s1[nt] = 0.f;
        s2[nt] = 0.f;
    }
#pragma unroll
    for (int mt = 0; mt < 2; mt++) {
#pragma unroll
        for (int r = 0; r < 4; r++) {
            size_t base = (size_t)(row0 + mt * 16 + kg * 4 + r) * HD;
#pragma unroll
            for (int nt = 0; nt < 4; nt++) {
                int col = w * 64 + nt * 16 + lr;
                float v = acc[mt][nt][r] + bcol[nt] + hv[base + col];
                hv[base + col] = v;
                s1[nt] += v;
                s2[nt] += v * v;
            }
        }
    }
    if (accum_stats) {
#pragma unroll
        for (int nt = 0; nt < 4; nt++) {
            s1[nt] += __shfl_xor(s1[nt], 16);
            s1[nt] += __shfl_xor(s1[nt], 32);
            s2[nt] += __shfl_xor(s2[nt], 16);
            s2[nt] += __shfl_xor(s2[nt], 32);
        }
        if (l < 16) {
#pragma unroll
            for (int nt = 0; nt < 4; nt++) {
                int col = w * 64 + nt * 16 + l;
                atomicAdd(&stats_next[col], s1[nt]);
                atomicAdd(&stats_next[HD + col], s2[nt]);
            }
        }
    }
}

// ---------------- graph mean-pool ----------------
__global__ __launch_bounds__(256) void pool_kernel(const float* __restrict__ hv,
                                                   const int* __restrict__ gid,
                                                   float* __restrict__ hg,
                                                   float* __restrict__ cnt) {
    int c = threadIdx.x;
    int n0 = blockIdx.x * 32;
    int curg = gid[n0];
    float s = 0.f;
    int runlen = 0;
    for (int i = 0; i < 32; i++) {
        int n = n0 + i;
        int g = gid[n];
        if (g != curg) {
            atomicAdd(&hg[curg * HD + c], s);
            if (c == 0) atomicAdd(&cnt[curg], (float)runlen);
            curg = g;
            s = 0.f;
            runlen = 0;
        }
        s += hv[(size_t)n * HD + c];
        runlen++;
    }
    atomicAdd(&hg[curg * HD + c], s);
    if (c == 0) atomicAdd(&cnt[curg], (float)runlen);
}

// ---------------- final projection ----------------
__global__ __launch_bounds__(128) void out_kernel(const float* __restrict__ hg,
                                                  const float* __restrict__ cnt,
                                                  const float* __restrict__ wout,
                                                  const float* __restrict__ bout,
                                                  float* __restrict__ out) {
    __shared__ float hr[HD];
    int g = blockIdx.x, o = threadIdx.x;
    float inv = 1.0f / fmaxf(cnt[g], 1.0f);
    hr[o] = hg[g * HD + o] * inv;
    hr[o + 128] = hg[g * HD + o + 128] * inv;
    __syncthreads();
    float acc = bout[o];
#pragma unroll 4
    for (int k = 0; k < HD; k++) acc = fmaf(hr[k], wout[k * NOUT + o], acc);
    out[g * NOUT + o] = acc;
}

extern "C" void kernel_launch(void* const* d_in, const int* in_sizes, int n_in,
                              void* d_out, int out_size, void* d_ws, size_t ws_size,
                              hipStream_t stream) {
    const int* node_feats = (const int*)d_in[0];
    const int* edge_feats = (const int*)d_in[1];
    const int* src = (const int*)d_in[2];
    const int* dst = (const int*)d_in[3];
    const int* gid = (const int*)d_in[4];
    const float* atom_emb = (const float*)d_in[5];
    const float* bond_emb = (const float*)d_in[6];
    const float* gamma = (const float*)d_in[7];
    const float* beta = (const float*)d_in[8];
    const float* mlp_w = (const float*)d_in[9];
    const float* mlp_b = (const float*)d_in[10];
    const float* w_out = (const float*)d_in[11];
    const float* b_out = (const float*)d_in[12];
    float* out = (float*)d_out;

    float* ws = (float*)d_ws;
    float* hv = ws;
    float* x = hv + (size_t)N_NODES * HD;
    float* hetabs = x + (size_t)N_NODES * HD;
    int* row_ptr = (int*)(hetabs + NLAYERS * 125 * HD);
    int* cursor = row_ptr + (N_NODES + 1);
    int* src_sorted = cursor + N_NODES;
    int* combo_sorted = src_sorted + N_EDGES;
    int* hist = combo_sorted + N_EDGES;
    float* stats = (float*)(hist + N_NODES);        // [NLAYERS][2][HD]
    float* hg = stats + NLAYERS * 2 * HD;           // [NGRAPH][HD]
    float* cnt = hg + NGRAPH * HD;                  // [NGRAPH]
    // 16B-aligned bf16 W^T buffer
    uintptr_t wt_addr = ((uintptr_t)(cnt + NGRAPH) + 15) & ~(uintptr_t)15;
    ushort* Wt = (ushort*)wt_addr;                  // [NLAYERS][HD(n)][HD(k)]

    size_t zero_bytes = (size_t)(N_NODES + NLAYERS * 2 * HD + NGRAPH * HD + NGRAPH) * 4;
    hipMemsetAsync(hist, 0, zero_bytes, stream);

    hist_kernel<<<(N_EDGES + 255) / 256, 256, 0, stream>>>(dst, hist);
    scan_kernel<<<1, 1024, 0, stream>>>(hist, row_ptr, cursor);
    scatter_kernel<<<(N_EDGES + 255) / 256, 256, 0, stream>>>(dst, src, edge_feats, cursor,
                                                              src_sorted, combo_sorted);
    hetab_kernel<<<(NLAYERS * 125 * HD + 255) / 256, 256, 0, stream>>>(bond_emb, hetabs);
    wt_kernel<<<NLAYERS * HD, 256, 0, stream>>>(mlp_w, Wt);
    atom_kernel<<<N_NODES / 32, 256, 0, stream>>>(node_feats, atom_emb, hv, stats);

    for (int l = 0; l < NLAYERS; l++) {
        edge_kernel<<<N_NODES, 256, 0, stream>>>(hv, x, row_ptr, src_sorted, combo_sorted,
                                                 hetabs + l * 125 * HD, stats + l * 2 * HD,
                                                 gamma + l * HD, beta + l * HD);
        mlp_mfma_kernel<<<N_NODES / 32, 256, 0, stream>>>(x, hv, Wt + (size_t)l * HD * HD,
                                                          mlp_b + l * HD, stats + (l + 1) * 2 * HD,
                                                          (l < NLAYERS - 1) ? 1 : 0);
    }

    pool_kernel<<<N_NODES / 32, 256, 0, stream>>>(hv, gid, hg, cnt);
    out_kernel<<<NGRAPH, 128, 0, stream>>>(hg, cnt, w_out, b_out, out);
}

// Round 4
// 985.814 us; speedup vs baseline: 1.3518x; 1.0338x over previous
//
#include <hip/hip_runtime.h>

#define N_NODES 20000
#define N_EDGES 320000
#define HD 256
#define NLAYERS 7
#define NGRAPH 512
#define NOUT 128

typedef __attribute__((ext_vector_type(8))) short bf16x8;
typedef __attribute__((ext_vector_type(4))) int i32x4;
typedef __attribute__((ext_vector_type(4))) float f32x4;

__device__ __forceinline__ ushort f2bf(float f) {
    union { float f; unsigned u; } v;
    v.f = f;
    unsigned r = (v.u + 0x7FFFu + ((v.u >> 16) & 1u)) >> 16;
    return (ushort)r;
}
__device__ __forceinline__ float bf2f(ushort u) {
    union { unsigned u; float f; } v;
    v.u = (unsigned)u << 16;
    return v.f;
}

// ---------------- CSR build ----------------
__global__ __launch_bounds__(256) void hist_kernel(const int* __restrict__ dst, int* __restrict__ hist) {
    int e = blockIdx.x * 256 + threadIdx.x;
    if (e < N_EDGES) atomicAdd(&hist[dst[e]], 1);
}

__global__ __launch_bounds__(1024) void scan_kernel(const int* __restrict__ hist,
                                                    int* __restrict__ row_ptr,
                                                    int* __restrict__ cursor) {
    __shared__ int sums[1024];
    int t = threadIdx.x;
    const int CH = 20;
    int base = t * CH;
    int local[20];
    int s = 0;
#pragma unroll
    for (int i = 0; i < CH; i++) {
        int v = (base + i < N_NODES) ? hist[base + i] : 0;
        local[i] = s;
        s += v;
    }
    sums[t] = s;
    __syncthreads();
    for (int off = 1; off < 1024; off <<= 1) {
        int v = (t >= off) ? sums[t - off] : 0;
        __syncthreads();
        sums[t] += v;
        __syncthreads();
    }
    int offset = (t == 0) ? 0 : sums[t - 1];
#pragma unroll
    for (int i = 0; i < CH; i++) {
        int idx = base + i;
        if (idx < N_NODES) {
            int v = offset + local[i];
            row_ptr[idx] = v;
            cursor[idx] = v;
        }
    }
    if (t == 1023) row_ptr[N_NODES] = sums[1023];
}

__global__ __launch_bounds__(256) void scatter_kernel(const int* __restrict__ dst,
                                                      const int* __restrict__ src,
                                                      const int* __restrict__ ef,
                                                      int* __restrict__ cursor,
                                                      int* __restrict__ src_sorted,
                                                      int* __restrict__ combo_sorted) {
    int e = blockIdx.x * 256 + threadIdx.x;
    if (e < N_EDGES) {
        int d = dst[e];
        int p = atomicAdd(&cursor[d], 1);
        src_sorted[p] = src[e];
        combo_sorted[p] = ef[e * 3] * 25 + ef[e * 3 + 1] * 5 + ef[e * 3 + 2];
    }
}

// ---------------- bond-embedding combo tables (bf16): [L][125][H] ----------------
__global__ __launch_bounds__(256) void hetab_kernel(const float* __restrict__ bond,
                                                    ushort* __restrict__ he) {
    int idx = blockIdx.x * 256 + threadIdx.x;
    if (idx >= NLAYERS * 125 * HD) return;
    int h = idx & (HD - 1);
    int rem = idx >> 8;
    int l = rem / 125;
    int c = rem - l * 125;
    int f0 = c / 25, f1 = (c / 5) % 5, f2 = c % 5;
    const float* b = bond + (size_t)l * 3 * 8 * HD;
    he[idx] = f2bf(b[(0 * 8 + f0) * HD + h] + b[(1 * 8 + f1) * HD + h] + b[(2 * 8 + f2) * HD + h]);
}

// ---------------- W -> Wt bf16 transpose: Wt[l][n][k] ----------------
__global__ __launch_bounds__(256) void wt_kernel(const float* __restrict__ W,
                                                 ushort* __restrict__ Wt) {
    int b = blockIdx.x;
    int l = b >> 8;
    int n = b & 255;
    int k = threadIdx.x;
    float v = W[((size_t)l * HD + k) * HD + n];
    Wt[((size_t)l * HD + n) * HD + k] = f2bf(v);
}

// ---------------- atom encoder + layer-0 BN stats ----------------
__global__ __launch_bounds__(256) void atom_kernel(const int* __restrict__ nf,
                                                   const float* __restrict__ emb,
                                                   float* __restrict__ hv,
                                                   float* __restrict__ stats0) {
    int c = threadIdx.x;
    int n0 = blockIdx.x * 32;
    float s1 = 0.f, s2 = 0.f;
    for (int i = 0; i < 32; i++) {
        int n = n0 + i;
        const int* f = nf + n * 9;
        float v = 0.f;
#pragma unroll
        for (int j = 0; j < 9; j++) v += emb[(j * 128 + f[j]) * HD + c];
        hv[(size_t)n * HD + c] = v;
        s1 += v;
        s2 += v * v;
    }
    atomicAdd(&stats0[c], s1);
    atomicAdd(&stats0[HD + c], s2);
}

// ---------------- BN+ReLU -> bf16 h1 ----------------
__global__ __launch_bounds__(256) void bn_kernel(const float* __restrict__ hv,
                                                 const float* __restrict__ stats,
                                                 const float* __restrict__ gamma,
                                                 const float* __restrict__ beta,
                                                 ushort* __restrict__ h1) {
    int tid = blockIdx.x * 256 + threadIdx.x;  // N*HD/8 threads
    int idx = tid * 8;
    int c = idx & (HD - 1);
    float4 f0 = *reinterpret_cast<const float4*>(hv + idx);
    float4 f1 = *reinterpret_cast<const float4*>(hv + idx + 4);
    float v[8] = {f0.x, f0.y, f0.z, f0.w, f1.x, f1.y, f1.z, f1.w};
    ushort o[8];
#pragma unroll
    for (int j = 0; j < 8; j++) {
        float mu = stats[c + j] * (1.0f / N_NODES);
        float var = stats[HD + c + j] * (1.0f / N_NODES) - mu * mu;
        float a = gamma[c + j] * rsqrtf(fmaxf(var, 0.f) + 1e-5f);
        float b = beta[c + j] - mu * a;
        o[j] = f2bf(fmaxf(fmaf(v[j], a, b), 0.f));
    }
    i32x4 pack;
    pack.x = (int)o[0] | ((int)o[1] << 16);
    pack.y = (int)o[2] | ((int)o[3] << 16);
    pack.z = (int)o[4] | ((int)o[5] << 16);
    pack.w = (int)o[6] | ((int)o[7] << 16);
    *reinterpret_cast<i32x4*>(h1 + idx) = pack;
}

// ---------------- edge pass: no-max softmax (BN bounds m), bf16 gathers ----------------
__global__ __launch_bounds__(256) void edge_kernel(const ushort* __restrict__ h1,
                                                   ushort* __restrict__ xbf,
                                                   const int* __restrict__ row_ptr,
                                                   const int* __restrict__ src_sorted,
                                                   const int* __restrict__ combo_sorted,
                                                   const ushort* __restrict__ hetab) {
    int n = blockIdx.x;
    int c = threadIdx.x;
    int e0 = row_ptr[n], e1 = row_ptr[n + 1];
    float S = 0.f, T = 0.f;
    for (int e = e0; e < e1; e++) {
        int s = src_sorted[e];
        int cb = combo_sorted[e];
        float h1s = bf2f(h1[(size_t)s * HD + c]);
        float he = bf2f(hetab[cb * HD + c]);
        float m = fmaxf(h1s + he, 0.f) + 1e-7f;
        float ee = __expf(m);
        S += ee;
        T = fmaf(m, ee, T);
    }
    float agg = (S > 0.f) ? (T / S) : 0.f;
    float own = bf2f(h1[(size_t)n * HD + c]);
    xbf[(size_t)n * HD + c] = f2bf(own + agg);
}

// ---------------- MFMA MLP: hv += x @ W + b, fused BN stats ----------------
__global__ __launch_bounds__(256) void mlp_mfma_kernel(const ushort* __restrict__ xbf,
                                                       float* __restrict__ hv,
                                                       const ushort* __restrict__ Wt,
                                                       const float* __restrict__ bias,
                                                       float* __restrict__ stats_next,
                                                       int accum_stats) {
    // 32 rows x 256 cols per block; 4 waves, wave w owns cols [64w, 64w+64)
    __shared__ __attribute__((aligned(16))) ushort xs[32 * 256];  // bf16, XOR-swizzled 16B units

    int t = threadIdx.x;
    int row0 = blockIdx.x * 32;
    const ushort* xbase = xbf + (size_t)row0 * HD;

    // stage bf16 x -> LDS.  unit = 8 bf16 = 16B; swizzle unit ^= (row&7)
#pragma unroll
    for (int i = 0; i < 4; i++) {
        int flat = i * 2048 + t * 8;
        i32x4 iv = *reinterpret_cast<const i32x4*>(xbase + flat);
        int row = flat >> 8;
        int k8 = (flat >> 3) & 31;
        int sw = k8 ^ (row & 7);
        *reinterpret_cast<i32x4*>(&xs[row * 256 + sw * 8]) = iv;
    }
    __syncthreads();

    int l = t & 63;
    int w = t >> 6;
    int kg = l >> 4;         // k-group 0..3
    int lr = l & 15;         // row (A) / col (B/D) within tile

    f32x4 acc[2][4];
#pragma unroll
    for (int m = 0; m < 2; m++)
#pragma unroll
        for (int n = 0; n < 4; n++) acc[m][n] = (f32x4){0.f, 0.f, 0.f, 0.f};

    const ushort* wcol = Wt + (size_t)(w * 64 + lr) * HD;

#pragma unroll
    for (int ks = 0; ks < 8; ks++) {
        int unit = ks * 4 + kg;
        int rA0 = lr, rA1 = 16 + lr;
        bf16x8 a0 = *reinterpret_cast<const bf16x8*>(&xs[rA0 * 256 + (unit ^ (rA0 & 7)) * 8]);
        bf16x8 a1 = *reinterpret_cast<const bf16x8*>(&xs[rA1 * 256 + (unit ^ (rA1 & 7)) * 8]);
        int kk = ks * 32 + kg * 8;
        bf16x8 b0 = *reinterpret_cast<const bf16x8*>(wcol + kk);
        bf16x8 b1 = *reinterpret_cast<const bf16x8*>(wcol + 16 * HD + kk);
        bf16x8 b2 = *reinterpret_cast<const bf16x8*>(wcol + 32 * HD + kk);
        bf16x8 b3 = *reinterpret_cast<const bf16x8*>(wcol + 48 * HD + kk);
        acc[0][0] = __builtin_amdgcn_mfma_f32_16x16x32_bf16(a0, b0, acc[0][0], 0, 0, 0);
        acc[0][1] = __builtin_amdgcn_mfma_f32_16x16x32_bf16(a0, b1, acc[0][1], 0, 0, 0);
        acc[0][2] = __builtin_amdgcn_mfma_f32_16x16x32_bf16(a0, b2, acc[0][2], 0, 0, 0);
        acc[0][3] = __builtin_amdgcn_mfma_f32_16x16x32_bf16(a0, b3, acc[0][3], 0, 0, 0);
        acc[1][0] = __builtin_amdgcn_mfma_f32_16x16x32_bf16(a1, b0, acc[1][0], 0, 0, 0);
        acc[1][1] = __builtin_amdgcn_mfma_f32_16x16x32_bf16(a1, b1, acc[1][1], 0, 0, 0);
        acc[1][2] = __builtin_amdgcn_mfma_f32_16x16x32_bf16(a1, b2, acc[1][2], 0, 0, 0);
        acc[1][3] = __builtin_amdgcn_mfma_f32_16x16x32_bf16(a1, b3, acc[1][3], 0, 0, 0);
    }

    // epilogue: bias + residual + BN stats.  D layout: col=lr, row=kg*4+reg
    float bcol[4], s1[4], s2[4];
#pragma unroll
    for (int nt = 0; nt < 4; nt++) {
        bcol[nt] = bias[w * 64 + nt * 16 + lr];
        s1[nt] = 0.f;
        s2[nt] = 0.f;
    }
#pragma unroll
    for (int mt = 0; mt < 2; mt++) {
#pragma unroll
        for (int r = 0; r < 4; r++) {
            size_t base = (size_t)(row0 + mt * 16 + kg * 4 + r) * HD;
#pragma unroll
            for (int nt = 0; nt < 4; nt++) {
                int col = w * 64 + nt * 16 + lr;
                float v = acc[mt][nt][r] + bcol[nt] + hv[base + col];
                hv[base + col] = v;
                s1[nt] += v;
                s2[nt] += v * v;
            }
        }
    }
    if (accum_stats) {
#pragma unroll
        for (int nt = 0; nt < 4; nt++) {
            s1[nt] += __shfl_xor(s1[nt], 16);
            s1[nt] += __shfl_xor(s1[nt], 32);
            s2[nt] += __shfl_xor(s2[nt], 16);
            s2[nt] += __shfl_xor(s2[nt], 32);
        }
        if (l < 16) {
#pragma unroll
            for (int nt = 0; nt < 4; nt++) {
                int col = w * 64 + nt * 16 + l;
                atomicAdd(&stats_next[col], s1[nt]);
                atomicAdd(&stats_next[HD + col], s2[nt]);
            }
        }
    }
}

// ---------------- graph mean-pool ----------------
__global__ __launch_bounds__(256) void pool_kernel(const float* __restrict__ hv,
                                                   const int* __restrict__ gid,
                                                   float* __restrict__ hg,
                                                   float* __restrict__ cnt) {
    int c = threadIdx.x;
    int n0 = blockIdx.x * 32;
    int curg = gid[n0];
    float s = 0.f;
    int runlen = 0;
    for (int i = 0; i < 32; i++) {
        int n = n0 + i;
        int g = gid[n];
        if (g != curg) {
            atomicAdd(&hg[curg * HD + c], s);
            if (c == 0) atomicAdd(&cnt[curg], (float)runlen);
            curg = g;
            s = 0.f;
            runlen = 0;
        }
        s += hv[(size_t)n * HD + c];
        runlen++;
    }
    atomicAdd(&hg[curg * HD + c], s);
    if (c == 0) atomicAdd(&cnt[curg], (float)runlen);
}

// ---------------- final projection ----------------
__global__ __launch_bounds__(128) void out_kernel(const float* __restrict__ hg,
                                                  const float* __restrict__ cnt,
                                                  const float* __restrict__ wout,
                                                  const float* __restrict__ bout,
                                                  float* __restrict__ out) {
    __shared__ float hr[HD];
    int g = blockIdx.x, o = threadIdx.x;
    float inv = 1.0f / fmaxf(cnt[g], 1.0f);
    hr[o] = hg[g * HD + o] * inv;
    hr[o + 128] = hg[g * HD + o + 128] * inv;
    __syncthreads();
    float acc = bout[o];
#pragma unroll 4
    for (int k = 0; k < HD; k++) acc = fmaf(hr[k], wout[k * NOUT + o], acc);
    out[g * NOUT + o] = acc;
}

extern "C" void kernel_launch(void* const* d_in, const int* in_sizes, int n_in,
                              void* d_out, int out_size, void* d_ws, size_t ws_size,
                              hipStream_t stream) {
    const int* node_feats = (const int*)d_in[0];
    const int* edge_feats = (const int*)d_in[1];
    const int* src = (const int*)d_in[2];
    const int* dst = (const int*)d_in[3];
    const int* gid = (const int*)d_in[4];
    const float* atom_emb = (const float*)d_in[5];
    const float* bond_emb = (const float*)d_in[6];
    const float* gamma = (const float*)d_in[7];
    const float* beta = (const float*)d_in[8];
    const float* mlp_w = (const float*)d_in[9];
    const float* mlp_b = (const float*)d_in[10];
    const float* w_out = (const float*)d_in[11];
    const float* b_out = (const float*)d_in[12];
    float* out = (float*)d_out;

    float* ws = (float*)d_ws;
    float* hv = ws;                                   // [N][HD] f32
    ushort* h1 = (ushort*)(hv + (size_t)N_NODES * HD);    // [N][HD] bf16
    ushort* xbf = h1 + (size_t)N_NODES * HD;              // [N][HD] bf16
    ushort* Wt = xbf + (size_t)N_NODES * HD;              // [L][HD(n)][HD(k)] bf16
    ushort* hetabs = Wt + (size_t)NLAYERS * HD * HD;      // [L][125][HD] bf16
    int* row_ptr = (int*)(hetabs + NLAYERS * 125 * HD);
    int* cursor = row_ptr + (N_NODES + 1);
    int* src_sorted = cursor + N_NODES;
    int* combo_sorted = src_sorted + N_EDGES;
    int* hist = combo_sorted + N_EDGES;
    float* stats = (float*)(hist + N_NODES);          // [L][2][HD]
    float* hg = stats + NLAYERS * 2 * HD;             // [G][HD]
    float* cnt = hg + NGRAPH * HD;                    // [G]

    size_t zero_bytes = (size_t)(N_NODES + NLAYERS * 2 * HD + NGRAPH * HD + NGRAPH) * 4;
    hipMemsetAsync(hist, 0, zero_bytes, stream);

    hist_kernel<<<(N_EDGES + 255) / 256, 256, 0, stream>>>(dst, hist);
    scan_kernel<<<1, 1024, 0, stream>>>(hist, row_ptr, cursor);
    scatter_kernel<<<(N_EDGES + 255) / 256, 256, 0, stream>>>(dst, src, edge_feats, cursor,
                                                              src_sorted, combo_sorted);
    hetab_kernel<<<(NLAYERS * 125 * HD + 255) / 256, 256, 0, stream>>>(bond_emb, hetabs);
    wt_kernel<<<NLAYERS * HD, 256, 0, stream>>>(mlp_w, Wt);
    atom_kernel<<<N_NODES / 32, 256, 0, stream>>>(node_feats, atom_emb, hv, stats);

    for (int l = 0; l < NLAYERS; l++) {
        bn_kernel<<<N_NODES * HD / 8 / 256, 256, 0, stream>>>(hv, stats + l * 2 * HD,
                                                              gamma + l * HD, beta + l * HD, h1);
        edge_kernel<<<N_NODES, 256, 0, stream>>>(h1, xbf, row_ptr, src_sorted, combo_sorted,
                                                 hetabs + (size_t)l * 125 * HD);
        mlp_mfma_kernel<<<N_NODES / 32, 256, 0, stream>>>(xbf, hv, Wt + (size_t)l * HD * HD,
                                                          mlp_b + l * HD, stats + (l + 1) * 2 * HD,
                                                          (l < NLAYERS - 1) ? 1 : 0);
    }

    pool_kernel<<<N_NODES / 32, 256, 0, stream>>>(hv, gid, hg, cnt);
    out_kernel<<<NGRAPH, 128, 0, stream>>>(hg, cnt, w_out, b_out, out);
}

// Round 5
// 778.507 us; speedup vs baseline: 1.7117x; 1.2663x over previous
//
#include <hip/hip_runtime.h>

#define N_NODES 20000
#define N_EDGES 320000
#define HD 256
#define NLAYERS 7
#define NGRAPH 512
#define NOUT 128

typedef __attribute__((ext_vector_type(8))) short bf16x8;
typedef __attribute__((ext_vector_type(4))) int i32x4;
typedef __attribute__((ext_vector_type(4))) float f32x4;

__device__ __forceinline__ ushort f2bf(float f) {
    union { float f; unsigned u; } v;
    v.f = f;
    unsigned r = (v.u + 0x7FFFu + ((v.u >> 16) & 1u)) >> 16;
    return (ushort)r;
}
__device__ __forceinline__ float bf2f(ushort u) {
    union { unsigned u; float f; } v;
    v.u = (unsigned)u << 16;
    return v.f;
}
__device__ __forceinline__ float bflo(unsigned p) {
    union { unsigned u; float f; } v;
    v.u = p << 16;
    return v.f;
}
__device__ __forceinline__ float bfhi(unsigned p) {
    union { unsigned u; float f; } v;
    v.u = p & 0xffff0000u;
    return v.f;
}

// ---------------- CSR build ----------------
__global__ __launch_bounds__(256) void hist_kernel(const int* __restrict__ dst, int* __restrict__ hist) {
    int e = blockIdx.x * 256 + threadIdx.x;
    if (e < N_EDGES) atomicAdd(&hist[dst[e]], 1);
}

__global__ __launch_bounds__(1024) void scan_kernel(const int* __restrict__ hist,
                                                    int* __restrict__ row_ptr,
                                                    int* __restrict__ cursor) {
    __shared__ int sums[1024];
    int t = threadIdx.x;
    const int CH = 20;
    int base = t * CH;
    int local[20];
    int s = 0;
#pragma unroll
    for (int i = 0; i < CH; i++) {
        int v = (base + i < N_NODES) ? hist[base + i] : 0;
        local[i] = s;
        s += v;
    }
    sums[t] = s;
    __syncthreads();
    for (int off = 1; off < 1024; off <<= 1) {
        int v = (t >= off) ? sums[t - off] : 0;
        __syncthreads();
        sums[t] += v;
        __syncthreads();
    }
    int offset = (t == 0) ? 0 : sums[t - 1];
#pragma unroll
    for (int i = 0; i < CH; i++) {
        int idx = base + i;
        if (idx < N_NODES) {
            int v = offset + local[i];
            row_ptr[idx] = v;
            cursor[idx] = v;
        }
    }
    if (t == 1023) row_ptr[N_NODES] = sums[1023];
}

__global__ __launch_bounds__(256) void scatter_kernel(const int* __restrict__ dst,
                                                      const int* __restrict__ src,
                                                      const int* __restrict__ ef,
                                                      int* __restrict__ cursor,
                                                      int* __restrict__ src_sorted,
                                                      int* __restrict__ combo_sorted) {
    int e = blockIdx.x * 256 + threadIdx.x;
    if (e < N_EDGES) {
        int d = dst[e];
        int p = atomicAdd(&cursor[d], 1);
        src_sorted[p] = src[e];
        combo_sorted[p] = ef[e * 3] * 25 + ef[e * 3 + 1] * 5 + ef[e * 3 + 2];
    }
}

// ---------------- bond-embedding combo tables (bf16): [L][125][H] ----------------
__global__ __launch_bounds__(256) void hetab_kernel(const float* __restrict__ bond,
                                                    ushort* __restrict__ he) {
    int idx = blockIdx.x * 256 + threadIdx.x;
    if (idx >= NLAYERS * 125 * HD) return;
    int h = idx & (HD - 1);
    int rem = idx >> 8;
    int l = rem / 125;
    int c = rem - l * 125;
    int f0 = c / 25, f1 = (c / 5) % 5, f2 = c % 5;
    const float* b = bond + (size_t)l * 3 * 8 * HD;
    he[idx] = f2bf(b[(0 * 8 + f0) * HD + h] + b[(1 * 8 + f1) * HD + h] + b[(2 * 8 + f2) * HD + h]);
}

// ---------------- W -> Wt bf16 transpose: Wt[l][n][k] ----------------
__global__ __launch_bounds__(256) void wt_kernel(const float* __restrict__ W,
                                                 ushort* __restrict__ Wt) {
    int b = blockIdx.x;
    int l = b >> 8;
    int n = b & 255;
    int k = threadIdx.x;
    float v = W[((size_t)l * HD + k) * HD + n];
    Wt[((size_t)l * HD + n) * HD + k] = f2bf(v);
}

// ---------------- atom encoder + layer-0 BN stats ----------------
__global__ __launch_bounds__(256) void atom_kernel(const int* __restrict__ nf,
                                                   const float* __restrict__ emb,
                                                   float* __restrict__ hv,
                                                   float* __restrict__ stats0) {
    int c = threadIdx.x;
    int n0 = blockIdx.x * 32;
    float s1 = 0.f, s2 = 0.f;
    for (int i = 0; i < 32; i++) {
        int n = n0 + i;
        const int* f = nf + n * 9;
        float v = 0.f;
#pragma unroll
        for (int j = 0; j < 9; j++) v += emb[(j * 128 + f[j]) * HD + c];
        hv[(size_t)n * HD + c] = v;
        s1 += v;
        s2 += v * v;
    }
    atomicAdd(&stats0[c], s1);
    atomicAdd(&stats0[HD + c], s2);
}

// ---------------- BN+ReLU -> bf16 h1 ----------------
__global__ __launch_bounds__(256) void bn_kernel(const float* __restrict__ hv,
                                                 const float* __restrict__ stats,
                                                 const float* __restrict__ gamma,
                                                 const float* __restrict__ beta,
                                                 ushort* __restrict__ h1) {
    int tid = blockIdx.x * 256 + threadIdx.x;  // N*HD/8 threads
    int idx = tid * 8;
    int c = idx & (HD - 1);
    float4 f0 = *reinterpret_cast<const float4*>(hv + idx);
    float4 f1 = *reinterpret_cast<const float4*>(hv + idx + 4);
    float v[8] = {f0.x, f0.y, f0.z, f0.w, f1.x, f1.y, f1.z, f1.w};
    ushort o[8];
#pragma unroll
    for (int j = 0; j < 8; j++) {
        float mu = stats[c + j] * (1.0f / N_NODES);
        float var = stats[HD + c + j] * (1.0f / N_NODES) - mu * mu;
        float a = gamma[c + j] * rsqrtf(fmaxf(var, 0.f) + 1e-5f);
        float b = beta[c + j] - mu * a;
        o[j] = f2bf(fmaxf(fmaf(v[j], a, b), 0.f));
    }
    i32x4 pack;
    pack.x = (int)o[0] | ((int)o[1] << 16);
    pack.y = (int)o[2] | ((int)o[3] << 16);
    pack.z = (int)o[4] | ((int)o[5] << 16);
    pack.w = (int)o[6] | ((int)o[7] << 16);
    *reinterpret_cast<i32x4*>(h1 + idx) = pack;
}

// ---------------- edge pass: wave-per-node, 4 ch/lane, software-pipelined ----------------
__global__ __launch_bounds__(256) void edge_kernel(const ushort* __restrict__ h1,
                                                   ushort* __restrict__ xbf,
                                                   const int* __restrict__ row_ptr,
                                                   const int* __restrict__ src_sorted,
                                                   const int* __restrict__ combo_sorted,
                                                   const ushort* __restrict__ hetab) {
    int wv = threadIdx.x >> 6;
    int lane = threadIdx.x & 63;
    int n = blockIdx.x * 4 + wv;
    int c4 = lane * 4;
    int e0 = row_ptr[n], e1 = row_ptr[n + 1];

    float S0 = 0.f, S1 = 0.f, S2 = 0.f, S3 = 0.f;
    float T0 = 0.f, T1 = 0.f, T2 = 0.f, T3 = 0.f;

    if (e0 < e1) {
        int s = src_sorted[e0];
        int cb = combo_sorted[e0];
        uint2 hs = *reinterpret_cast<const uint2*>(h1 + ((size_t)s << 8) + c4);
        uint2 hb = *reinterpret_cast<const uint2*>(hetab + (cb << 8) + c4);
        for (int e = e0; e < e1;) {
            uint2 chs = hs, chb = hb;
            ++e;
            if (e < e1) {
                int sn = src_sorted[e];
                int cbn = combo_sorted[e];
                hs = *reinterpret_cast<const uint2*>(h1 + ((size_t)sn << 8) + c4);
                hb = *reinterpret_cast<const uint2*>(hetab + (cbn << 8) + c4);
            }
            float m0 = fmaxf(bflo(chs.x) + bflo(chb.x), 0.f) + 1e-7f;
            float m1 = fmaxf(bfhi(chs.x) + bfhi(chb.x), 0.f) + 1e-7f;
            float m2 = fmaxf(bflo(chs.y) + bflo(chb.y), 0.f) + 1e-7f;
            float m3 = fmaxf(bfhi(chs.y) + bfhi(chb.y), 0.f) + 1e-7f;
            float e0f = __expf(m0);
            float e1f = __expf(m1);
            float e2f = __expf(m2);
            float e3f = __expf(m3);
            S0 += e0f; T0 = fmaf(m0, e0f, T0);
            S1 += e1f; T1 = fmaf(m1, e1f, T1);
            S2 += e2f; T2 = fmaf(m2, e2f, T2);
            S3 += e3f; T3 = fmaf(m3, e3f, T3);
        }
    }

    float a0 = (S0 > 0.f) ? (T0 / S0) : 0.f;
    float a1 = (S1 > 0.f) ? (T1 / S1) : 0.f;
    float a2 = (S2 > 0.f) ? (T2 / S2) : 0.f;
    float a3 = (S3 > 0.f) ? (T3 / S3) : 0.f;

    uint2 ho = *reinterpret_cast<const uint2*>(h1 + ((size_t)n << 8) + c4);
    unsigned o0 = f2bf(bflo(ho.x) + a0);
    unsigned o1 = f2bf(bfhi(ho.x) + a1);
    unsigned o2 = f2bf(bflo(ho.y) + a2);
    unsigned o3 = f2bf(bfhi(ho.y) + a3);
    uint2 res;
    res.x = o0 | (o1 << 16);
    res.y = o2 | (o3 << 16);
    *reinterpret_cast<uint2*>(xbf + ((size_t)n << 8) + c4) = res;
}

// ---------------- MFMA MLP: hv += x @ W + b, fused BN stats ----------------
__global__ __launch_bounds__(256) void mlp_mfma_kernel(const ushort* __restrict__ xbf,
                                                       float* __restrict__ hv,
                                                       const ushort* __restrict__ Wt,
                                                       const float* __restrict__ bias,
                                                       float* __restrict__ stats_next,
                                                       int accum_stats) {
    // 32 rows x 256 cols per block; 4 waves, wave w owns cols [64w, 64w+64)
    __shared__ __attribute__((aligned(16))) ushort xs[32 * 256];  // bf16, XOR-swizzled 16B units

    int t = threadIdx.x;
    int row0 = blockIdx.x * 32;
    const ushort* xbase = xbf + (size_t)row0 * HD;

    // stage bf16 x -> LDS.  unit = 8 bf16 = 16B; swizzle unit ^= (row&7)
#pragma unroll
    for (int i = 0; i < 4; i++) {
        int flat = i * 2048 + t * 8;
        i32x4 iv = *reinterpret_cast<const i32x4*>(xbase + flat);
        int row = flat >> 8;
        int k8 = (flat >> 3) & 31;
        int sw = k8 ^ (row & 7);
        *reinterpret_cast<i32x4*>(&xs[row * 256 + sw * 8]) = iv;
    }
    __syncthreads();

    int l = t & 63;
    int w = t >> 6;
    int kg = l >> 4;         // k-group 0..3
    int lr = l & 15;         // row (A) / col (B/D) within tile

    f32x4 acc[2][4];
#pragma unroll
    for (int m = 0; m < 2; m++)
#pragma unroll
        for (int n = 0; n < 4; n++) acc[m][n] = (f32x4){0.f, 0.f, 0.f, 0.f};

    const ushort* wcol = Wt + (size_t)(w * 64 + lr) * HD;

#pragma unroll
    for (int ks = 0; ks < 8; ks++) {
        int unit = ks * 4 + kg;
        int rA0 = lr, rA1 = 16 + lr;
        bf16x8 a0 = *reinterpret_cast<const bf16x8*>(&xs[rA0 * 256 + (unit ^ (rA0 & 7)) * 8]);
        bf16x8 a1 = *reinterpret_cast<const bf16x8*>(&xs[rA1 * 256 + (unit ^ (rA1 & 7)) * 8]);
        int kk = ks * 32 + kg * 8;
        bf16x8 b0 = *reinterpret_cast<const bf16x8*>(wcol + kk);
        bf16x8 b1 = *reinterpret_cast<const bf16x8*>(wcol + 16 * HD + kk);
        bf16x8 b2 = *reinterpret_cast<const bf16x8*>(wcol + 32 * HD + kk);
        bf16x8 b3 = *reinterpret_cast<const bf16x8*>(wcol + 48 * HD + kk);
        acc[0][0] = __builtin_amdgcn_mfma_f32_16x16x32_bf16(a0, b0, acc[0][0], 0, 0, 0);
        acc[0][1] = __builtin_amdgcn_mfma_f32_16x16x32_bf16(a0, b1, acc[0][1], 0, 0, 0);
        acc[0][2] = __builtin_amdgcn_mfma_f32_16x16x32_bf16(a0, b2, acc[0][2], 0, 0, 0);
        acc[0][3] = __builtin_amdgcn_mfma_f32_16x16x32_bf16(a0, b3, acc[0][3], 0, 0, 0);
        acc[1][0] = __builtin_amdgcn_mfma_f32_16x16x32_bf16(a1, b0, acc[1][0], 0, 0, 0);
        acc[1][1] = __builtin_amdgcn_mfma_f32_16x16x32_bf16(a1, b1, acc[1][1], 0, 0, 0);
        acc[1][2] = __builtin_amdgcn_mfma_f32_16x16x32_bf16(a1, b2, acc[1][2], 0, 0, 0);
        acc[1][3] = __builtin_amdgcn_mfma_f32_16x16x32_bf16(a1, b3, acc[1][3], 0, 0, 0);
    }

    // epilogue: bias + residual + BN stats.  D layout: col=lr, row=kg*4+reg
    float bcol[4], s1[4], s2[4];
#pragma unroll
    for (int nt = 0; nt < 4; nt++) {
        bcol[nt] = bias[w * 64 + nt * 16 + lr];
        s1[nt] = 0.f;
        s2[nt] = 0.f;
    }
#pragma unroll
    for (int mt = 0; mt < 2; mt++) {
#pragma unroll
        for (int r = 0; r < 4; r++) {
            size_t base = (size_t)(row0 + mt * 16 + kg * 4 + r) * HD;
#pragma unroll
            for (int nt = 0; nt < 4; nt++) {
                int col = w * 64 + nt * 16 + lr;
                float v = acc[mt][nt][r] + bcol[nt] + hv[base + col];
                hv[base + col] = v;
                s1[nt] += v;
                s2[nt] += v * v;
            }
        }
    }
    if (accum_stats) {
#pragma unroll
        for (int nt = 0; nt < 4; nt++) {
            s1[nt] += __shfl_xor(s1[nt], 16);
            s1[nt] += __shfl_xor(s1[nt], 32);
            s2[nt] += __shfl_xor(s2[nt], 16);
            s2[nt] += __shfl_xor(s2[nt], 32);
        }
        if (l < 16) {
#pragma unroll
            for (int nt = 0; nt < 4; nt++) {
                int col = w * 64 + nt * 16 + l;
                atomicAdd(&stats_next[col], s1[nt]);
                atomicAdd(&stats_next[HD + col], s2[nt]);
            }
        }
    }
}

// ---------------- graph mean-pool ----------------
__global__ __launch_bounds__(256) void pool_kernel(const float* __restrict__ hv,
                                                   const int* __restrict__ gid,
                                                   float* __restrict__ hg,
                                                   float* __restrict__ cnt) {
    int c = threadIdx.x;
    int n0 = blockIdx.x * 32;
    int curg = gid[n0];
    float s = 0.f;
    int runlen = 0;
    for (int i = 0; i < 32; i++) {
        int n = n0 + i;
        int g = gid[n];
        if (g != curg) {
            atomicAdd(&hg[curg * HD + c], s);
            if (c == 0) atomicAdd(&cnt[curg], (float)runlen);
            curg = g;
            s = 0.f;
            runlen = 0;
        }
        s += hv[(size_t)n * HD + c];
        runlen++;
    }
    atomicAdd(&hg[curg * HD + c], s);
    if (c == 0) atomicAdd(&cnt[curg], (float)runlen);
}

// ---------------- final projection ----------------
__global__ __launch_bounds__(128) void out_kernel(const float* __restrict__ hg,
                                                  const float* __restrict__ cnt,
                                                  const float* __restrict__ wout,
                                                  const float* __restrict__ bout,
                                                  float* __restrict__ out) {
    __shared__ float hr[HD];
    int g = blockIdx.x, o = threadIdx.x;
    float inv = 1.0f / fmaxf(cnt[g], 1.0f);
    hr[o] = hg[g * HD + o] * inv;
    hr[o + 128] = hg[g * HD + o + 128] * inv;
    __syncthreads();
    float acc = bout[o];
#pragma unroll 4
    for (int k = 0; k < HD; k++) acc = fmaf(hr[k], wout[k * NOUT + o], acc);
    out[g * NOUT + o] = acc;
}

extern "C" void kernel_launch(void* const* d_in, const int* in_sizes, int n_in,
                              void* d_out, int out_size, void* d_ws, size_t ws_size,
                              hipStream_t stream) {
    const int* node_feats = (const int*)d_in[0];
    const int* edge_feats = (const int*)d_in[1];
    const int* src = (const int*)d_in[2];
    const int* dst = (const int*)d_in[3];
    const int* gid = (const int*)d_in[4];
    const float* atom_emb = (const float*)d_in[5];
    const float* bond_emb = (const float*)d_in[6];
    const float* gamma = (const float*)d_in[7];
    const float* beta = (const float*)d_in[8];
    const float* mlp_w = (const float*)d_in[9];
    const float* mlp_b = (const float*)d_in[10];
    const float* w_out = (const float*)d_in[11];
    const float* b_out = (const float*)d_in[12];
    float* out = (float*)d_out;

    float* ws = (float*)d_ws;
    float* hv = ws;                                   // [N][HD] f32
    ushort* h1 = (ushort*)(hv + (size_t)N_NODES * HD);    // [N][HD] bf16
    ushort* xbf = h1 + (size_t)N_NODES * HD;              // [N][HD] bf16
    ushort* Wt = xbf + (size_t)N_NODES * HD;              // [L][HD(n)][HD(k)] bf16
    ushort* hetabs = Wt + (size_t)NLAYERS * HD * HD;      // [L][125][HD] bf16
    int* row_ptr = (int*)(hetabs + NLAYERS * 125 * HD);
    int* cursor = row_ptr + (N_NODES + 1);
    int* src_sorted = cursor + N_NODES;
    int* combo_sorted = src_sorted + N_EDGES;
    int* hist = combo_sorted + N_EDGES;
    float* stats = (float*)(hist + N_NODES);          // [L][2][HD]
    float* hg = stats + NLAYERS * 2 * HD;             // [G][HD]
    float* cnt = hg + NGRAPH * HD;                    // [G]

    size_t zero_bytes = (size_t)(N_NODES + NLAYERS * 2 * HD + NGRAPH * HD + NGRAPH) * 4;
    hipMemsetAsync(hist, 0, zero_bytes, stream);

    hist_kernel<<<(N_EDGES + 255) / 256, 256, 0, stream>>>(dst, hist);
    scan_kernel<<<1, 1024, 0, stream>>>(hist, row_ptr, cursor);
    scatter_kernel<<<(N_EDGES + 255) / 256, 256, 0, stream>>>(dst, src, edge_feats, cursor,
                                                              src_sorted, combo_sorted);
    hetab_kernel<<<(NLAYERS * 125 * HD + 255) / 256, 256, 0, stream>>>(bond_emb, hetabs);
    wt_kernel<<<NLAYERS * HD, 256, 0, stream>>>(mlp_w, Wt);
    atom_kernel<<<N_NODES / 32, 256, 0, stream>>>(node_feats, atom_emb, hv, stats);

    for (int l = 0; l < NLAYERS; l++) {
        bn_kernel<<<N_NODES * HD / 8 / 256, 256, 0, stream>>>(hv, stats + l * 2 * HD,
                                                              gamma + l * HD, beta + l * HD, h1);
        edge_kernel<<<N_NODES / 4, 256, 0, stream>>>(h1, xbf, row_ptr, src_sorted, combo_sorted,
                                                     hetabs + (size_t)l * 125 * HD);
        mlp_mfma_kernel<<<N_NODES / 32, 256, 0, stream>>>(xbf, hv, Wt + (size_t)l * HD * HD,
                                                          mlp_b + l * HD, stats + (l + 1) * 2 * HD,
                                                          (l < NLAYERS - 1) ? 1 : 0);
    }

    pool_kernel<<<N_NODES / 32, 256, 0, stream>>>(hv, gid, hg, cnt);
    out_kernel<<<NGRAPH, 128, 0, stream>>>(hg, cnt, w_out, b_out, out);
}

// Round 6
// 662.611 us; speedup vs baseline: 2.0111x; 1.1749x over previous
//
#include <hip/hip_runtime.h>

#define N_NODES 20000
#define N_EDGES 320000
#define HD 256
#define NLAYERS 7
#define NGRAPH 512
#define NOUT 128

typedef __attribute__((ext_vector_type(8))) short bf16x8;
typedef __attribute__((ext_vector_type(4))) int i32x4;
typedef __attribute__((ext_vector_type(4))) float f32x4;

__device__ __forceinline__ ushort f2bf(float f) {
    union { float f; unsigned u; } v;
    v.f = f;
    unsigned r = (v.u + 0x7FFFu + ((v.u >> 16) & 1u)) >> 16;
    return (ushort)r;
}
__device__ __forceinline__ float bf2f(ushort u) {
    union { unsigned u; float f; } v;
    v.u = (unsigned)u << 16;
    return v.f;
}
__device__ __forceinline__ float bflo(unsigned p) {
    union { unsigned u; float f; } v;
    v.u = p << 16;
    return v.f;
}
__device__ __forceinline__ float bfhi(unsigned p) {
    union { unsigned u; float f; } v;
    v.u = p & 0xffff0000u;
    return v.f;
}

// ---------------- CSR build ----------------
__global__ __launch_bounds__(256) void hist_kernel(const int* __restrict__ dst, int* __restrict__ hist) {
    int e = blockIdx.x * 256 + threadIdx.x;
    if (e < N_EDGES) atomicAdd(&hist[dst[e]], 1);
}

__global__ __launch_bounds__(1024) void scan_kernel(const int* __restrict__ hist,
                                                    int* __restrict__ row_ptr,
                                                    int* __restrict__ cursor) {
    __shared__ int sums[1024];
    int t = threadIdx.x;
    const int CH = 20;
    int base = t * CH;
    int local[20];
    int s = 0;
#pragma unroll
    for (int i = 0; i < CH; i++) {
        int v = (base + i < N_NODES) ? hist[base + i] : 0;
        local[i] = s;
        s += v;
    }
    sums[t] = s;
    __syncthreads();
    for (int off = 1; off < 1024; off <<= 1) {
        int v = (t >= off) ? sums[t - off] : 0;
        __syncthreads();
        sums[t] += v;
        __syncthreads();
    }
    int offset = (t == 0) ? 0 : sums[t - 1];
#pragma unroll
    for (int i = 0; i < CH; i++) {
        int idx = base + i;
        if (idx < N_NODES) {
            int v = offset + local[i];
            row_ptr[idx] = v;
            cursor[idx] = v;
        }
    }
    if (t == 1023) row_ptr[N_NODES] = sums[1023];
}

// pack = src | (combo << 15)   (src < 32768, combo < 125)
__global__ __launch_bounds__(256) void scatter_kernel(const int* __restrict__ dst,
                                                      const int* __restrict__ src,
                                                      const int* __restrict__ ef,
                                                      int* __restrict__ cursor,
                                                      unsigned* __restrict__ pack_sorted) {
    int e = blockIdx.x * 256 + threadIdx.x;
    if (e < N_EDGES) {
        int d = dst[e];
        int p = atomicAdd(&cursor[d], 1);
        unsigned cb = (unsigned)(ef[e * 3] * 25 + ef[e * 3 + 1] * 5 + ef[e * 3 + 2]);
        pack_sorted[p] = (unsigned)src[e] | (cb << 15);
    }
}

// ---------------- bond-embedding combo tables (bf16): [L][125][H] ----------------
__global__ __launch_bounds__(256) void hetab_kernel(const float* __restrict__ bond,
                                                    ushort* __restrict__ he) {
    int idx = blockIdx.x * 256 + threadIdx.x;
    if (idx >= NLAYERS * 125 * HD) return;
    int h = idx & (HD - 1);
    int rem = idx >> 8;
    int l = rem / 125;
    int c = rem - l * 125;
    int f0 = c / 25, f1 = (c / 5) % 5, f2 = c % 5;
    const float* b = bond + (size_t)l * 3 * 8 * HD;
    he[idx] = f2bf(b[(0 * 8 + f0) * HD + h] + b[(1 * 8 + f1) * HD + h] + b[(2 * 8 + f2) * HD + h]);
}

// ---------------- W -> Wt bf16 transpose: Wt[l][n][k] ----------------
__global__ __launch_bounds__(256) void wt_kernel(const float* __restrict__ W,
                                                 ushort* __restrict__ Wt) {
    int b = blockIdx.x;
    int l = b >> 8;
    int n = b & 255;
    int k = threadIdx.x;
    float v = W[((size_t)l * HD + k) * HD + n];
    Wt[((size_t)l * HD + n) * HD + k] = f2bf(v);
}

// ---------------- atom encoder + layer-0 BN stats ----------------
__global__ __launch_bounds__(256) void atom_kernel(const int* __restrict__ nf,
                                                   const float* __restrict__ emb,
                                                   float* __restrict__ hv,
                                                   float* __restrict__ stats0) {
    int c = threadIdx.x;
    int n0 = blockIdx.x * 32;
    float s1 = 0.f, s2 = 0.f;
    for (int i = 0; i < 32; i++) {
        int n = n0 + i;
        const int* f = nf + n * 9;
        float v = 0.f;
#pragma unroll
        for (int j = 0; j < 9; j++) v += emb[(j * 128 + f[j]) * HD + c];
        hv[(size_t)n * HD + c] = v;
        s1 += v;
        s2 += v * v;
    }
    atomicAdd(&stats0[c], s1);
    atomicAdd(&stats0[HD + c], s2);
}

// ---------------- BN+ReLU -> bf16 h1 ----------------
__global__ __launch_bounds__(256) void bn_kernel(const float* __restrict__ hv,
                                                 const float* __restrict__ stats,
                                                 const float* __restrict__ gamma,
                                                 const float* __restrict__ beta,
                                                 ushort* __restrict__ h1) {
    int tid = blockIdx.x * 256 + threadIdx.x;  // N*HD/8 threads
    int idx = tid * 8;
    int c = idx & (HD - 1);
    float4 f0 = *reinterpret_cast<const float4*>(hv + idx);
    float4 f1 = *reinterpret_cast<const float4*>(hv + idx + 4);
    float v[8] = {f0.x, f0.y, f0.z, f0.w, f1.x, f1.y, f1.z, f1.w};
    ushort o[8];
#pragma unroll
    for (int j = 0; j < 8; j++) {
        float mu = stats[c + j] * (1.0f / N_NODES);
        float var = stats[HD + c + j] * (1.0f / N_NODES) - mu * mu;
        float a = gamma[c + j] * rsqrtf(fmaxf(var, 0.f) + 1e-5f);
        float b = beta[c + j] - mu * a;
        o[j] = f2bf(fmaxf(fmaf(v[j], a, b), 0.f));
    }
    i32x4 pack;
    pack.x = (int)o[0] | ((int)o[1] << 16);
    pack.y = (int)o[2] | ((int)o[3] << 16);
    pack.z = (int)o[4] | ((int)o[5] << 16);
    pack.w = (int)o[6] | ((int)o[7] << 16);
    *reinterpret_cast<i32x4*>(h1 + idx) = pack;
}

// ---------------- edge pass: wave/node, 4ch/lane, 64-edge index preload, 4-deep gathers ----
__global__ __launch_bounds__(256) void edge_kernel(const ushort* __restrict__ h1,
                                                   ushort* __restrict__ xbf,
                                                   const int* __restrict__ row_ptr,
                                                   const unsigned* __restrict__ pack_sorted,
                                                   const ushort* __restrict__ hetab) {
    int wv = threadIdx.x >> 6;
    int lane = threadIdx.x & 63;
    int n = blockIdx.x * 4 + wv;
    int c4 = lane * 4;
    int e0 = row_ptr[n];
    int deg = row_ptr[n + 1] - e0;

    float S0 = 0.f, S1 = 0.f, S2 = 0.f, S3 = 0.f;
    float T0 = 0.f, T1 = 0.f, T2 = 0.f, T3 = 0.f;

#define EDGE_PROC(HS, HB)                                                  \
    {                                                                      \
        float m0 = fmaxf(bflo(HS.x) + bflo(HB.x), 0.f);                    \
        float m1 = fmaxf(bfhi(HS.x) + bfhi(HB.x), 0.f);                    \
        float m2 = fmaxf(bflo(HS.y) + bflo(HB.y), 0.f);                    \
        float m3 = fmaxf(bfhi(HS.y) + bfhi(HB.y), 0.f);                    \
        float x0 = __expf(m0), x1 = __expf(m1), x2 = __expf(m2), x3 = __expf(m3); \
        S0 += x0; T0 = fmaf(m0, x0, T0);                                   \
        S1 += x1; T1 = fmaf(m1, x1, T1);                                   \
        S2 += x2; T2 = fmaf(m2, x2, T2);                                   \
        S3 += x3; T3 = fmaf(m3, x3, T3);                                   \
    }

    for (int base = 0; base < deg; base += 64) {
        int cnt = min(64, deg - base);
        unsigned pk = (lane < cnt) ? pack_sorted[e0 + base + lane] : 0u;
        int j = 0;
        for (; j + 4 <= cnt; j += 4) {
            unsigned p0 = __shfl(pk, j + 0);
            unsigned p1 = __shfl(pk, j + 1);
            unsigned p2 = __shfl(pk, j + 2);
            unsigned p3 = __shfl(pk, j + 3);
            uint2 hs0 = *reinterpret_cast<const uint2*>(h1 + ((size_t)(p0 & 0x7FFFu) << 8) + c4);
            uint2 hb0 = *reinterpret_cast<const uint2*>(hetab + ((p0 >> 15) << 8) + c4);
            uint2 hs1 = *reinterpret_cast<const uint2*>(h1 + ((size_t)(p1 & 0x7FFFu) << 8) + c4);
            uint2 hb1 = *reinterpret_cast<const uint2*>(hetab + ((p1 >> 15) << 8) + c4);
            uint2 hs2 = *reinterpret_cast<const uint2*>(h1 + ((size_t)(p2 & 0x7FFFu) << 8) + c4);
            uint2 hb2 = *reinterpret_cast<const uint2*>(hetab + ((p2 >> 15) << 8) + c4);
            uint2 hs3 = *reinterpret_cast<const uint2*>(h1 + ((size_t)(p3 & 0x7FFFu) << 8) + c4);
            uint2 hb3 = *reinterpret_cast<const uint2*>(hetab + ((p3 >> 15) << 8) + c4);
            EDGE_PROC(hs0, hb0);
            EDGE_PROC(hs1, hb1);
            EDGE_PROC(hs2, hb2);
            EDGE_PROC(hs3, hb3);
        }
        for (; j < cnt; j++) {
            unsigned p0 = __shfl(pk, j);
            uint2 hs0 = *reinterpret_cast<const uint2*>(h1 + ((size_t)(p0 & 0x7FFFu) << 8) + c4);
            uint2 hb0 = *reinterpret_cast<const uint2*>(hetab + ((p0 >> 15) << 8) + c4);
            EDGE_PROC(hs0, hb0);
        }
    }
#undef EDGE_PROC

    // softmax weights are shift-invariant in the +1e-7; m is linear in it -> add at end
    float a0 = (S0 > 0.f) ? (T0 / S0 + 1e-7f) : 0.f;
    float a1 = (S1 > 0.f) ? (T1 / S1 + 1e-7f) : 0.f;
    float a2 = (S2 > 0.f) ? (T2 / S2 + 1e-7f) : 0.f;
    float a3 = (S3 > 0.f) ? (T3 / S3 + 1e-7f) : 0.f;

    uint2 ho = *reinterpret_cast<const uint2*>(h1 + ((size_t)n << 8) + c4);
    unsigned o0 = f2bf(bflo(ho.x) + a0);
    unsigned o1 = f2bf(bfhi(ho.x) + a1);
    unsigned o2 = f2bf(bflo(ho.y) + a2);
    unsigned o3 = f2bf(bfhi(ho.y) + a3);
    uint2 res;
    res.x = o0 | (o1 << 16);
    res.y = o2 | (o3 << 16);
    *reinterpret_cast<uint2*>(xbf + ((size_t)n << 8) + c4) = res;
}

// ---------------- MFMA MLP: hv += x @ W + b, residual prefetched, fused BN stats ----------
__global__ __launch_bounds__(256) void mlp_mfma_kernel(const ushort* __restrict__ xbf,
                                                       float* __restrict__ hv,
                                                       const ushort* __restrict__ Wt,
                                                       const float* __restrict__ bias,
                                                       float* __restrict__ stats_next,
                                                       int accum_stats) {
    // 32 rows x 256 cols per block; 4 waves, wave w owns cols [64w, 64w+64)
    __shared__ __attribute__((aligned(16))) ushort xs[32 * 256];  // bf16, XOR-swizzled 16B units

    int t = threadIdx.x;
    int row0 = blockIdx.x * 32;
    const ushort* xbase = xbf + (size_t)row0 * HD;

    // stage bf16 x -> LDS.  unit = 8 bf16 = 16B; swizzle unit ^= (row&7)
#pragma unroll
    for (int i = 0; i < 4; i++) {
        int flat = i * 2048 + t * 8;
        i32x4 iv = *reinterpret_cast<const i32x4*>(xbase + flat);
        int row = flat >> 8;
        int k8 = (flat >> 3) & 31;
        int sw = k8 ^ (row & 7);
        *reinterpret_cast<i32x4*>(&xs[row * 256 + sw * 8]) = iv;
    }

    int l = t & 63;
    int w = t >> 6;
    int kg = l >> 4;         // k-group 0..3
    int lr = l & 15;         // row (A) / col (B/D) within tile

    // prefetch residual + bias BEFORE the MFMA loop so latency hides under compute
    float res[2][4][4];  // [mt][r][nt]
    float bcol[4];
#pragma unroll
    for (int nt = 0; nt < 4; nt++) bcol[nt] = bias[w * 64 + nt * 16 + lr];
#pragma unroll
    for (int mt = 0; mt < 2; mt++)
#pragma unroll
        for (int r = 0; r < 4; r++) {
            size_t base = (size_t)(row0 + mt * 16 + kg * 4 + r) * HD;
#pragma unroll
            for (int nt = 0; nt < 4; nt++)
                res[mt][r][nt] = hv[base + w * 64 + nt * 16 + lr];
        }

    __syncthreads();

    f32x4 acc[2][4];
#pragma unroll
    for (int m = 0; m < 2; m++)
#pragma unroll
        for (int n = 0; n < 4; n++) acc[m][n] = (f32x4){0.f, 0.f, 0.f, 0.f};

    const ushort* wcol = Wt + (size_t)(w * 64 + lr) * HD;

#pragma unroll
    for (int ks = 0; ks < 8; ks++) {
        int unit = ks * 4 + kg;
        int rA0 = lr, rA1 = 16 + lr;
        bf16x8 a0 = *reinterpret_cast<const bf16x8*>(&xs[rA0 * 256 + (unit ^ (rA0 & 7)) * 8]);
        bf16x8 a1 = *reinterpret_cast<const bf16x8*>(&xs[rA1 * 256 + (unit ^ (rA1 & 7)) * 8]);
        int kk = ks * 32 + kg * 8;
        bf16x8 b0 = *reinterpret_cast<const bf16x8*>(wcol + kk);
        bf16x8 b1 = *reinterpret_cast<const bf16x8*>(wcol + 16 * HD + kk);
        bf16x8 b2 = *reinterpret_cast<const bf16x8*>(wcol + 32 * HD + kk);
        bf16x8 b3 = *reinterpret_cast<const bf16x8*>(wcol + 48 * HD + kk);
        acc[0][0] = __builtin_amdgcn_mfma_f32_16x16x32_bf16(a0, b0, acc[0][0], 0, 0, 0);
        acc[0][1] = __builtin_amdgcn_mfma_f32_16x16x32_bf16(a0, b1, acc[0][1], 0, 0, 0);
        acc[0][2] = __builtin_amdgcn_mfma_f32_16x16x32_bf16(a0, b2, acc[0][2], 0, 0, 0);
        acc[0][3] = __builtin_amdgcn_mfma_f32_16x16x32_bf16(a0, b3, acc[0][3], 0, 0, 0);
        acc[1][0] = __builtin_amdgcn_mfma_f32_16x16x32_bf16(a1, b0, acc[1][0], 0, 0, 0);
        acc[1][1] = __builtin_amdgcn_mfma_f32_16x16x32_bf16(a1, b1, acc[1][1], 0, 0, 0);
        acc[1][2] = __builtin_amdgcn_mfma_f32_16x16x32_bf16(a1, b2, acc[1][2], 0, 0, 0);
        acc[1][3] = __builtin_amdgcn_mfma_f32_16x16x32_bf16(a1, b3, acc[1][3], 0, 0, 0);
    }

    // epilogue: bias + residual + BN stats.  D layout: col=lr, row=kg*4+reg
    float s1[4], s2[4];
#pragma unroll
    for (int nt = 0; nt < 4; nt++) { s1[nt] = 0.f; s2[nt] = 0.f; }
#pragma unroll
    for (int mt = 0; mt < 2; mt++) {
#pragma unroll
        for (int r = 0; r < 4; r++) {
            size_t base = (size_t)(row0 + mt * 16 + kg * 4 + r) * HD;
#pragma unroll
            for (int nt = 0; nt < 4; nt++) {
                int col = w * 64 + nt * 16 + lr;
                float v = acc[mt][nt][r] + bcol[nt] + res[mt][r][nt];
                hv[base + col] = v;
                s1[nt] += v;
                s2[nt] += v * v;
            }
        }
    }
    if (accum_stats) {
#pragma unroll
        for (int nt = 0; nt < 4; nt++) {
            s1[nt] += __shfl_xor(s1[nt], 16);
            s1[nt] += __shfl_xor(s1[nt], 32);
            s2[nt] += __shfl_xor(s2[nt], 16);
            s2[nt] += __shfl_xor(s2[nt], 32);
        }
        if (l < 16) {
#pragma unroll
            for (int nt = 0; nt < 4; nt++) {
                int col = w * 64 + nt * 16 + l;
                atomicAdd(&stats_next[col], s1[nt]);
                atomicAdd(&stats_next[HD + col], s2[nt]);
            }
        }
    }
}

// ---------------- graph mean-pool ----------------
__global__ __launch_bounds__(256) void pool_kernel(const float* __restrict__ hv,
                                                   const int* __restrict__ gid,
                                                   float* __restrict__ hg,
                                                   float* __restrict__ cnt) {
    int c = threadIdx.x;
    int n0 = blockIdx.x * 32;
    int curg = gid[n0];
    float s = 0.f;
    int runlen = 0;
    for (int i = 0; i < 32; i++) {
        int n = n0 + i;
        int g = gid[n];
        if (g != curg) {
            atomicAdd(&hg[curg * HD + c], s);
            if (c == 0) atomicAdd(&cnt[curg], (float)runlen);
            curg = g;
            s = 0.f;
            runlen = 0;
        }
        s += hv[(size_t)n * HD + c];
        runlen++;
    }
    atomicAdd(&hg[curg * HD + c], s);
    if (c == 0) atomicAdd(&cnt[curg], (float)runlen);
}

// ---------------- final projection ----------------
__global__ __launch_bounds__(128) void out_kernel(const float* __restrict__ hg,
                                                  const float* __restrict__ cnt,
                                                  const float* __restrict__ wout,
                                                  const float* __restrict__ bout,
                                                  float* __restrict__ out) {
    __shared__ float hr[HD];
    int g = blockIdx.x, o = threadIdx.x;
    float inv = 1.0f / fmaxf(cnt[g], 1.0f);
    hr[o] = hg[g * HD + o] * inv;
    hr[o + 128] = hg[g * HD + o + 128] * inv;
    __syncthreads();
    float acc = bout[o];
#pragma unroll 4
    for (int k = 0; k < HD; k++) acc = fmaf(hr[k], wout[k * NOUT + o], acc);
    out[g * NOUT + o] = acc;
}

extern "C" void kernel_launch(void* const* d_in, const int* in_sizes, int n_in,
                              void* d_out, int out_size, void* d_ws, size_t ws_size,
                              hipStream_t stream) {
    const int* node_feats = (const int*)d_in[0];
    const int* edge_feats = (const int*)d_in[1];
    const int* src = (const int*)d_in[2];
    const int* dst = (const int*)d_in[3];
    const int* gid = (const int*)d_in[4];
    const float* atom_emb = (const float*)d_in[5];
    const float* bond_emb = (const float*)d_in[6];
    const float* gamma = (const float*)d_in[7];
    const float* beta = (const float*)d_in[8];
    const float* mlp_w = (const float*)d_in[9];
    const float* mlp_b = (const float*)d_in[10];
    const float* w_out = (const float*)d_in[11];
    const float* b_out = (const float*)d_in[12];
    float* out = (float*)d_out;

    float* ws = (float*)d_ws;
    float* hv = ws;                                       // [N][HD] f32
    ushort* h1 = (ushort*)(hv + (size_t)N_NODES * HD);    // [N][HD] bf16
    ushort* xbf = h1 + (size_t)N_NODES * HD;              // [N][HD] bf16
    ushort* Wt = xbf + (size_t)N_NODES * HD;              // [L][HD(n)][HD(k)] bf16
    ushort* hetabs = Wt + (size_t)NLAYERS * HD * HD;      // [L][125][HD] bf16
    int* row_ptr = (int*)(hetabs + NLAYERS * 125 * HD);
    int* cursor = row_ptr + (N_NODES + 1);
    unsigned* pack_sorted = (unsigned*)(cursor + N_NODES);
    int* hist = (int*)(pack_sorted + N_EDGES);
    float* stats = (float*)(hist + N_NODES);              // [L][2][HD]
    float* hg = stats + NLAYERS * 2 * HD;                 // [G][HD]
    float* cnt = hg + NGRAPH * HD;                        // [G]

    size_t zero_bytes = (size_t)(N_NODES + NLAYERS * 2 * HD + NGRAPH * HD + NGRAPH) * 4;
    hipMemsetAsync(hist, 0, zero_bytes, stream);

    hist_kernel<<<(N_EDGES + 255) / 256, 256, 0, stream>>>(dst, hist);
    scan_kernel<<<1, 1024, 0, stream>>>(hist, row_ptr, cursor);
    scatter_kernel<<<(N_EDGES + 255) / 256, 256, 0, stream>>>(dst, src, edge_feats, cursor,
                                                              pack_sorted);
    hetab_kernel<<<(NLAYERS * 125 * HD + 255) / 256, 256, 0, stream>>>(bond_emb, hetabs);
    wt_kernel<<<NLAYERS * HD, 256, 0, stream>>>(mlp_w, Wt);
    atom_kernel<<<N_NODES / 32, 256, 0, stream>>>(node_feats, atom_emb, hv, stats);

    for (int l = 0; l < NLAYERS; l++) {
        bn_kernel<<<N_NODES * HD / 8 / 256, 256, 0, stream>>>(hv, stats + l * 2 * HD,
                                                              gamma + l * HD, beta + l * HD, h1);
        edge_kernel<<<N_NODES / 4, 256, 0, stream>>>(h1, xbf, row_ptr, pack_sorted,
                                                     hetabs + (size_t)l * 125 * HD);
        mlp_mfma_kernel<<<N_NODES / 32, 256, 0, stream>>>(xbf, hv, Wt + (size_t)l * HD * HD,
                                                          mlp_b + l * HD, stats + (l + 1) * 2 * HD,
                                                          (l < NLAYERS - 1) ? 1 : 0);
    }

    pool_kernel<<<N_NODES / 32, 256, 0, stream>>>(hv, gid, hg, cnt);
    out_kernel<<<NGRAPH, 128, 0, stream>>>(hg, cnt, w_out, b_out, out);
}

// Round 7
// 630.215 us; speedup vs baseline: 2.1145x; 1.0514x over previous
//
#include <hip/hip_runtime.h>

#define N_NODES 20000
#define N_EDGES 320000
#define HD 256
#define NLAYERS 7
#define NGRAPH 512
#define NOUT 128

typedef __attribute__((ext_vector_type(8))) short bf16x8;
typedef __attribute__((ext_vector_type(4))) int i32x4;
typedef __attribute__((ext_vector_type(4))) float f32x4;

__device__ __forceinline__ ushort f2bf(float f) {
    union { float f; unsigned u; } v;
    v.f = f;
    unsigned r = (v.u + 0x7FFFu + ((v.u >> 16) & 1u)) >> 16;
    return (ushort)r;
}
__device__ __forceinline__ float bf2f(ushort u) {
    union { unsigned u; float f; } v;
    v.u = (unsigned)u << 16;
    return v.f;
}
__device__ __forceinline__ float bflo(unsigned p) {
    union { unsigned u; float f; } v;
    v.u = p << 16;
    return v.f;
}
__device__ __forceinline__ float bfhi(unsigned p) {
    union { unsigned u; float f; } v;
    v.u = p & 0xffff0000u;
    return v.f;
}

// ---------------- CSR build ----------------
__global__ __launch_bounds__(256) void hist_kernel(const int* __restrict__ dst, int* __restrict__ hist) {
    int e = blockIdx.x * 256 + threadIdx.x;
    if (e < N_EDGES) atomicAdd(&hist[dst[e]], 1);
}

__global__ __launch_bounds__(1024) void scan_kernel(const int* __restrict__ hist,
                                                    int* __restrict__ row_ptr,
                                                    int* __restrict__ cursor) {
    __shared__ int sums[1024];
    int t = threadIdx.x;
    const int CH = 20;
    int base = t * CH;
    int local[20];
    int s = 0;
#pragma unroll
    for (int i = 0; i < CH; i++) {
        int v = (base + i < N_NODES) ? hist[base + i] : 0;
        local[i] = s;
        s += v;
    }
    sums[t] = s;
    __syncthreads();
    for (int off = 1; off < 1024; off <<= 1) {
        int v = (t >= off) ? sums[t - off] : 0;
        __syncthreads();
        sums[t] += v;
        __syncthreads();
    }
    int offset = (t == 0) ? 0 : sums[t - 1];
#pragma unroll
    for (int i = 0; i < CH; i++) {
        int idx = base + i;
        if (idx < N_NODES) {
            int v = offset + local[i];
            row_ptr[idx] = v;
            cursor[idx] = v;
        }
    }
    if (t == 1023) row_ptr[N_NODES] = sums[1023];
}

// pack = src | (combo << 15)   (src < 32768, combo < 125)
__global__ __launch_bounds__(256) void scatter_kernel(const int* __restrict__ dst,
                                                      const int* __restrict__ src,
                                                      const int* __restrict__ ef,
                                                      int* __restrict__ cursor,
                                                      unsigned* __restrict__ pack_sorted) {
    int e = blockIdx.x * 256 + threadIdx.x;
    if (e < N_EDGES) {
        int d = dst[e];
        int p = atomicAdd(&cursor[d], 1);
        unsigned cb = (unsigned)(ef[e * 3] * 25 + ef[e * 3 + 1] * 5 + ef[e * 3 + 2]);
        pack_sorted[p] = (unsigned)src[e] | (cb << 15);
    }
}

// ---------------- bond-embedding combo tables (bf16): [L][125][H] ----------------
__global__ __launch_bounds__(256) void hetab_kernel(const float* __restrict__ bond,
                                                    ushort* __restrict__ he) {
    int idx = blockIdx.x * 256 + threadIdx.x;
    if (idx >= NLAYERS * 125 * HD) return;
    int h = idx & (HD - 1);
    int rem = idx >> 8;
    int l = rem / 125;
    int c = rem - l * 125;
    int f0 = c / 25, f1 = (c / 5) % 5, f2 = c % 5;
    const float* b = bond + (size_t)l * 3 * 8 * HD;
    he[idx] = f2bf(b[(0 * 8 + f0) * HD + h] + b[(1 * 8 + f1) * HD + h] + b[(2 * 8 + f2) * HD + h]);
}

// ---- W -> Wt2 bf16, k-slice-major: Wt2[l][ks][n][kg][8], ks=k>>5, kg=(k>>3)&3, j=k&7 ----
// A wave's B-fragment load (lanes (kg,lr), 16B each) is then one contiguous 1KB block.
__global__ __launch_bounds__(256) void wt_kernel(const float* __restrict__ W,
                                                 ushort* __restrict__ Wt) {
    int b = blockIdx.x;
    int l = b >> 8;
    int n = b & 255;
    int k = threadIdx.x;
    float v = W[((size_t)l * HD + k) * HD + n];
    int ks = k >> 5, kg = (k >> 3) & 3, j = k & 7;
    Wt[(((size_t)l * 8 + ks) * 256 + n) * 32 + kg * 8 + j] = f2bf(v);
}

// ---------------- atom encoder + layer-0 BN stats ----------------
__global__ __launch_bounds__(256) void atom_kernel(const int* __restrict__ nf,
                                                   const float* __restrict__ emb,
                                                   float* __restrict__ hv,
                                                   float* __restrict__ stats0) {
    int c = threadIdx.x;
    int n0 = blockIdx.x * 32;
    float s1 = 0.f, s2 = 0.f;
    for (int i = 0; i < 32; i++) {
        int n = n0 + i;
        const int* f = nf + n * 9;
        float v = 0.f;
#pragma unroll
        for (int j = 0; j < 9; j++) v += emb[(j * 128 + f[j]) * HD + c];
        hv[(size_t)n * HD + c] = v;
        s1 += v;
        s2 += v * v;
    }
    atomicAdd(&stats0[c], s1);
    atomicAdd(&stats0[HD + c], s2);
}

// ---------------- BN+ReLU -> bf16 h1 ----------------
__global__ __launch_bounds__(256) void bn_kernel(const float* __restrict__ hv,
                                                 const float* __restrict__ stats,
                                                 const float* __restrict__ gamma,
                                                 const float* __restrict__ beta,
                                                 ushort* __restrict__ h1) {
    int tid = blockIdx.x * 256 + threadIdx.x;  // N*HD/8 threads
    int idx = tid * 8;
    int c = idx & (HD - 1);
    float4 f0 = *reinterpret_cast<const float4*>(hv + idx);
    float4 f1 = *reinterpret_cast<const float4*>(hv + idx + 4);
    float v[8] = {f0.x, f0.y, f0.z, f0.w, f1.x, f1.y, f1.z, f1.w};
    ushort o[8];
#pragma unroll
    for (int j = 0; j < 8; j++) {
        float mu = stats[c + j] * (1.0f / N_NODES);
        float var = stats[HD + c + j] * (1.0f / N_NODES) - mu * mu;
        float a = gamma[c + j] * rsqrtf(fmaxf(var, 0.f) + 1e-5f);
        float b = beta[c + j] - mu * a;
        o[j] = f2bf(fmaxf(fmaf(v[j], a, b), 0.f));
    }
    i32x4 pack;
    pack.x = (int)o[0] | ((int)o[1] << 16);
    pack.y = (int)o[2] | ((int)o[3] << 16);
    pack.z = (int)o[4] | ((int)o[5] << 16);
    pack.w = (int)o[6] | ((int)o[7] << 16);
    *reinterpret_cast<i32x4*>(h1 + idx) = pack;
}

// ---------------- edge pass: wave/node, 4ch/lane, 64-edge index preload, 4-deep gathers ----
__global__ __launch_bounds__(256) void edge_kernel(const ushort* __restrict__ h1,
                                                   ushort* __restrict__ xbf,
                                                   const int* __restrict__ row_ptr,
                                                   const unsigned* __restrict__ pack_sorted,
                                                   const ushort* __restrict__ hetab) {
    int wv = threadIdx.x >> 6;
    int lane = threadIdx.x & 63;
    int n = blockIdx.x * 4 + wv;
    int c4 = lane * 4;
    int e0 = row_ptr[n];
    int deg = row_ptr[n + 1] - e0;

    float S0 = 0.f, S1 = 0.f, S2 = 0.f, S3 = 0.f;
    float T0 = 0.f, T1 = 0.f, T2 = 0.f, T3 = 0.f;

#define EDGE_PROC(HS, HB)                                                  \
    {                                                                      \
        float m0 = fmaxf(bflo(HS.x) + bflo(HB.x), 0.f);                    \
        float m1 = fmaxf(bfhi(HS.x) + bfhi(HB.x), 0.f);                    \
        float m2 = fmaxf(bflo(HS.y) + bflo(HB.y), 0.f);                    \
        float m3 = fmaxf(bfhi(HS.y) + bfhi(HB.y), 0.f);                    \
        float x0 = __expf(m0), x1 = __expf(m1), x2 = __expf(m2), x3 = __expf(m3); \
        S0 += x0; T0 = fmaf(m0, x0, T0);                                   \
        S1 += x1; T1 = fmaf(m1, x1, T1);                                   \
        S2 += x2; T2 = fmaf(m2, x2, T2);                                   \
        S3 += x3; T3 = fmaf(m3, x3, T3);                                   \
    }

    for (int base = 0; base < deg; base += 64) {
        int cnt = min(64, deg - base);
        unsigned pk = (lane < cnt) ? pack_sorted[e0 + base + lane] : 0u;
        int j = 0;
        for (; j + 4 <= cnt; j += 4) {
            unsigned p0 = __shfl(pk, j + 0);
            unsigned p1 = __shfl(pk, j + 1);
            unsigned p2 = __shfl(pk, j + 2);
            unsigned p3 = __shfl(pk, j + 3);
            uint2 hs0 = *reinterpret_cast<const uint2*>(h1 + ((size_t)(p0 & 0x7FFFu) << 8) + c4);
            uint2 hb0 = *reinterpret_cast<const uint2*>(hetab + ((p0 >> 15) << 8) + c4);
            uint2 hs1 = *reinterpret_cast<const uint2*>(h1 + ((size_t)(p1 & 0x7FFFu) << 8) + c4);
            uint2 hb1 = *reinterpret_cast<const uint2*>(hetab + ((p1 >> 15) << 8) + c4);
            uint2 hs2 = *reinterpret_cast<const uint2*>(h1 + ((size_t)(p2 & 0x7FFFu) << 8) + c4);
            uint2 hb2 = *reinterpret_cast<const uint2*>(hetab + ((p2 >> 15) << 8) + c4);
            uint2 hs3 = *reinterpret_cast<const uint2*>(h1 + ((size_t)(p3 & 0x7FFFu) << 8) + c4);
            uint2 hb3 = *reinterpret_cast<const uint2*>(hetab + ((p3 >> 15) << 8) + c4);
            EDGE_PROC(hs0, hb0);
            EDGE_PROC(hs1, hb1);
            EDGE_PROC(hs2, hb2);
            EDGE_PROC(hs3, hb3);
        }
        for (; j < cnt; j++) {
            unsigned p0 = __shfl(pk, j);
            uint2 hs0 = *reinterpret_cast<const uint2*>(h1 + ((size_t)(p0 & 0x7FFFu) << 8) + c4);
            uint2 hb0 = *reinterpret_cast<const uint2*>(hetab + ((p0 >> 15) << 8) + c4);
            EDGE_PROC(hs0, hb0);
        }
    }
#undef EDGE_PROC

    // softmax weights are shift-invariant in the +1e-7; m is linear in it -> add at end
    float a0 = (S0 > 0.f) ? (T0 / S0 + 1e-7f) : 0.f;
    float a1 = (S1 > 0.f) ? (T1 / S1 + 1e-7f) : 0.f;
    float a2 = (S2 > 0.f) ? (T2 / S2 + 1e-7f) : 0.f;
    float a3 = (S3 > 0.f) ? (T3 / S3 + 1e-7f) : 0.f;

    uint2 ho = *reinterpret_cast<const uint2*>(h1 + ((size_t)n << 8) + c4);
    unsigned o0 = f2bf(bflo(ho.x) + a0);
    unsigned o1 = f2bf(bfhi(ho.x) + a1);
    unsigned o2 = f2bf(bflo(ho.y) + a2);
    unsigned o3 = f2bf(bfhi(ho.y) + a3);
    uint2 res;
    res.x = o0 | (o1 << 16);
    res.y = o2 | (o3 << 16);
    *reinterpret_cast<uint2*>(xbf + ((size_t)n << 8) + c4) = res;
}

// ---------------- MFMA MLP: hv += x @ W + b, B ping-pong prefetch, fused BN stats --------
__global__ __launch_bounds__(256, 3) void mlp_mfma_kernel(const ushort* __restrict__ xbf,
                                                          float* __restrict__ hv,
                                                          const ushort* __restrict__ Wt,
                                                          const float* __restrict__ bias,
                                                          float* __restrict__ stats_next,
                                                          int accum_stats) {
    // 32 rows x 256 cols per block; 4 waves, wave w owns cols [64w, 64w+64)
    __shared__ __attribute__((aligned(16))) ushort xs[32 * 256];  // bf16, XOR-swizzled 16B units

    int t = threadIdx.x;
    int row0 = blockIdx.x * 32;
    const ushort* xbase = xbf + (size_t)row0 * HD;

    // stage bf16 x -> LDS.  unit = 8 bf16 = 16B; swizzle unit ^= (row&7)
#pragma unroll
    for (int i = 0; i < 4; i++) {
        int flat = i * 2048 + t * 8;
        i32x4 iv = *reinterpret_cast<const i32x4*>(xbase + flat);
        int row = flat >> 8;
        int k8 = (flat >> 3) & 31;
        int sw = k8 ^ (row & 7);
        *reinterpret_cast<i32x4*>(&xs[row * 256 + sw * 8]) = iv;
    }

    int l = t & 63;
    int w = t >> 6;
    int kg = l >> 4;         // k-group 0..3
    int lr = l & 15;         // row (A) / col (B/D) within tile

    // Wt2[ks][n][kg][8]: this wave-lane's base; +ks*8192 per k-slice, +nt*512 per 16-col tile
    const ushort* wbase = Wt + ((size_t)(w * 64 + lr)) * 32 + kg * 8;

    bf16x8 bb0[4], bb1[4];
#define LOADB(dst, ks)                                                              \
    {                                                                               \
        dst[0] = *reinterpret_cast<const bf16x8*>(wbase + (ks) * 8192 + 0);         \
        dst[1] = *reinterpret_cast<const bf16x8*>(wbase + (ks) * 8192 + 512);       \
        dst[2] = *reinterpret_cast<const bf16x8*>(wbase + (ks) * 8192 + 1024);      \
        dst[3] = *reinterpret_cast<const bf16x8*>(wbase + (ks) * 8192 + 1536);      \
    }

    // issue first two B tile-loads before the barrier (overlap barrier + LDS drain)
    LOADB(bb0, 0)
    LOADB(bb1, 1)

    // prefetch residual + bias so their L3 latency hides under the MFMA loop
    float res[2][4][4];  // [mt][r][nt]
    float bcol[4];
#pragma unroll
    for (int nt = 0; nt < 4; nt++) bcol[nt] = bias[w * 64 + nt * 16 + lr];
#pragma unroll
    for (int mt = 0; mt < 2; mt++)
#pragma unroll
        for (int r = 0; r < 4; r++) {
            size_t base = (size_t)(row0 + mt * 16 + kg * 4 + r) * HD;
#pragma unroll
            for (int nt = 0; nt < 4; nt++)
                res[mt][r][nt] = hv[base + w * 64 + nt * 16 + lr];
        }

    __syncthreads();

    f32x4 acc[2][4];
#pragma unroll
    for (int m = 0; m < 2; m++)
#pragma unroll
        for (int n = 0; n < 4; n++) acc[m][n] = (f32x4){0.f, 0.f, 0.f, 0.f};

#define MFMASTEP(ks, B)                                                                          \
    {                                                                                            \
        int unit = (ks) * 4 + kg;                                                                \
        int rA0 = lr, rA1 = 16 + lr;                                                             \
        bf16x8 a0 = *reinterpret_cast<const bf16x8*>(&xs[rA0 * 256 + (unit ^ (rA0 & 7)) * 8]);   \
        bf16x8 a1 = *reinterpret_cast<const bf16x8*>(&xs[rA1 * 256 + (unit ^ (rA1 & 7)) * 8]);   \
        acc[0][0] = __builtin_amdgcn_mfma_f32_16x16x32_bf16(a0, B[0], acc[0][0], 0, 0, 0);       \
        acc[0][1] = __builtin_amdgcn_mfma_f32_16x16x32_bf16(a0, B[1], acc[0][1], 0, 0, 0);       \
        acc[0][2] = __builtin_amdgcn_mfma_f32_16x16x32_bf16(a0, B[2], acc[0][2], 0, 0, 0);       \
        acc[0][3] = __builtin_amdgcn_mfma_f32_16x16x32_bf16(a0, B[3], acc[0][3], 0, 0, 0);       \
        acc[1][0] = __builtin_amdgcn_mfma_f32_16x16x32_bf16(a1, B[0], acc[1][0], 0, 0, 0);       \
        acc[1][1] = __builtin_amdgcn_mfma_f32_16x16x32_bf16(a1, B[1], acc[1][1], 0, 0, 0);       \
        acc[1][2] = __builtin_amdgcn_mfma_f32_16x16x32_bf16(a1, B[2], acc[1][2], 0, 0, 0);       \
        acc[1][3] = __builtin_amdgcn_mfma_f32_16x16x32_bf16(a1, B[3], acc[1][3], 0, 0, 0);       \
    }

    MFMASTEP(0, bb0) LOADB(bb0, 2)
    MFMASTEP(1, bb1) LOADB(bb1, 3)
    MFMASTEP(2, bb0) LOADB(bb0, 4)
    MFMASTEP(3, bb1) LOADB(bb1, 5)
    MFMASTEP(4, bb0) LOADB(bb0, 6)
    MFMASTEP(5, bb1) LOADB(bb1, 7)
    MFMASTEP(6, bb0)
    MFMASTEP(7, bb1)
#undef LOADB
#undef MFMASTEP

    // epilogue: bias + residual + BN stats.  D layout: col=lr, row=kg*4+reg
    float s1[4], s2[4];
#pragma unroll
    for (int nt = 0; nt < 4; nt++) { s1[nt] = 0.f; s2[nt] = 0.f; }
#pragma unroll
    for (int mt = 0; mt < 2; mt++) {
#pragma unroll
        for (int r = 0; r < 4; r++) {
            size_t base = (size_t)(row0 + mt * 16 + kg * 4 + r) * HD;
#pragma unroll
            for (int nt = 0; nt < 4; nt++) {
                int col = w * 64 + nt * 16 + lr;
                float v = acc[mt][nt][r] + bcol[nt] + res[mt][r][nt];
                hv[base + col] = v;
                s1[nt] += v;
                s2[nt] += v * v;
            }
        }
    }
    if (accum_stats) {
#pragma unroll
        for (int nt = 0; nt < 4; nt++) {
            s1[nt] += __shfl_xor(s1[nt], 16);
            s1[nt] += __shfl_xor(s1[nt], 32);
            s2[nt] += __shfl_xor(s2[nt], 16);
            s2[nt] += __shfl_xor(s2[nt], 32);
        }
        if (l < 16) {
#pragma unroll
            for (int nt = 0; nt < 4; nt++) {
                int col = w * 64 + nt * 16 + l;
                atomicAdd(&stats_next[col], s1[nt]);
                atomicAdd(&stats_next[HD + col], s2[nt]);
            }
        }
    }
}

// ---------------- graph mean-pool ----------------
__global__ __launch_bounds__(256) void pool_kernel(const float* __restrict__ hv,
                                                   const int* __restrict__ gid,
                                                   float* __restrict__ hg,
                                                   float* __restrict__ cnt) {
    int c = threadIdx.x;
    int n0 = blockIdx.x * 32;
    int curg = gid[n0];
    float s = 0.f;
    int runlen = 0;
    for (int i = 0; i < 32; i++) {
        int n = n0 + i;
        int g = gid[n];
        if (g != curg) {
            atomicAdd(&hg[curg * HD + c], s);
            if (c == 0) atomicAdd(&cnt[curg], (float)runlen);
            curg = g;
            s = 0.f;
            runlen = 0;
        }
        s += hv[(size_t)n * HD + c];
        runlen++;
    }
    atomicAdd(&hg[curg * HD + c], s);
    if (c == 0) atomicAdd(&cnt[curg], (float)runlen);
}

// ---------------- final projection ----------------
__global__ __launch_bounds__(128) void out_kernel(const float* __restrict__ hg,
                                                  const float* __restrict__ cnt,
                                                  const float* __restrict__ wout,
                                                  const float* __restrict__ bout,
                                                  float* __restrict__ out) {
    __shared__ float hr[HD];
    int g = blockIdx.x, o = threadIdx.x;
    float inv = 1.0f / fmaxf(cnt[g], 1.0f);
    hr[o] = hg[g * HD + o] * inv;
    hr[o + 128] = hg[g * HD + o + 128] * inv;
    __syncthreads();
    float acc = bout[o];
#pragma unroll 4
    for (int k = 0; k < HD; k++) acc = fmaf(hr[k], wout[k * NOUT + o], acc);
    out[g * NOUT + o] = acc;
}

extern "C" void kernel_launch(void* const* d_in, const int* in_sizes, int n_in,
                              void* d_out, int out_size, void* d_ws, size_t ws_size,
                              hipStream_t stream) {
    const int* node_feats = (const int*)d_in[0];
    const int* edge_feats = (const int*)d_in[1];
    const int* src = (const int*)d_in[2];
    const int* dst = (const int*)d_in[3];
    const int* gid = (const int*)d_in[4];
    const float* atom_emb = (const float*)d_in[5];
    const float* bond_emb = (const float*)d_in[6];
    const float* gamma = (const float*)d_in[7];
    const float* beta = (const float*)d_in[8];
    const float* mlp_w = (const float*)d_in[9];
    const float* mlp_b = (const float*)d_in[10];
    const float* w_out = (const float*)d_in[11];
    const float* b_out = (const float*)d_in[12];
    float* out = (float*)d_out;

    float* ws = (float*)d_ws;
    float* hv = ws;                                       // [N][HD] f32
    ushort* h1 = (ushort*)(hv + (size_t)N_NODES * HD);    // [N][HD] bf16
    ushort* xbf = h1 + (size_t)N_NODES * HD;              // [N][HD] bf16
    ushort* Wt = xbf + (size_t)N_NODES * HD;              // [L][8][256][32] bf16 (k-slice-major)
    ushort* hetabs = Wt + (size_t)NLAYERS * HD * HD;      // [L][125][HD] bf16
    int* row_ptr = (int*)(hetabs + NLAYERS * 125 * HD);
    int* cursor = row_ptr + (N_NODES + 1);
    unsigned* pack_sorted = (unsigned*)(cursor + N_NODES);
    int* hist = (int*)(pack_sorted + N_EDGES);
    float* stats = (float*)(hist + N_NODES);              // [L][2][HD]
    float* hg = stats + NLAYERS * 2 * HD;                 // [G][HD]
    float* cnt = hg + NGRAPH * HD;                        // [G]

    size_t zero_bytes = (size_t)(N_NODES + NLAYERS * 2 * HD + NGRAPH * HD + NGRAPH) * 4;
    hipMemsetAsync(hist, 0, zero_bytes, stream);

    hist_kernel<<<(N_EDGES + 255) / 256, 256, 0, stream>>>(dst, hist);
    scan_kernel<<<1, 1024, 0, stream>>>(hist, row_ptr, cursor);
    scatter_kernel<<<(N_EDGES + 255) / 256, 256, 0, stream>>>(dst, src, edge_feats, cursor,
                                                              pack_sorted);
    hetab_kernel<<<(NLAYERS * 125 * HD + 255) / 256, 256, 0, stream>>>(bond_emb, hetabs);
    wt_kernel<<<NLAYERS * HD, 256, 0, stream>>>(mlp_w, Wt);
    atom_kernel<<<N_NODES / 32, 256, 0, stream>>>(node_feats, atom_emb, hv, stats);

    for (int l = 0; l < NLAYERS; l++) {
        bn_kernel<<<N_NODES * HD / 8 / 256, 256, 0, stream>>>(hv, stats + l * 2 * HD,
                                                              gamma + l * HD, beta + l * HD, h1);
        edge_kernel<<<N_NODES / 4, 256, 0, stream>>>(h1, xbf, row_ptr, pack_sorted,
                                                     hetabs + (size_t)l * 125 * HD);
        mlp_mfma_kernel<<<N_NODES / 32, 256, 0, stream>>>(xbf, hv, Wt + (size_t)l * 8 * 256 * 32,
                                                          mlp_b + l * HD, stats + (l + 1) * 2 * HD,
                                                          (l < NLAYERS - 1) ? 1 : 0);
    }

    pool_kernel<<<N_NODES / 32, 256, 0, stream>>>(hv, gid, hg, cnt);
    out_kernel<<<NGRAPH, 128, 0, stream>>>(hg, cnt, w_out, b_out, out);
}